// Round 13
// baseline (471.132 us; speedup 1.0000x reference)
//
#include <hip/hip_runtime.h>
#include <math.h>

constexpr int kB = 4, kN = 4096, kK = 16;
constexpr int kRows = kB * kN;          // 16384
constexpr float kEps = 1e-5f;
constexpr float kFltMax = 3.402823466e38f;
constexpr int kCap = 240;               // per-query qualifier list (knn)

typedef __attribute__((ext_vector_type(8))) short short8;
typedef __attribute__((ext_vector_type(4))) float f32x4;

// bf16 round-half-up (2 ops vs 4 for RNE; <=1 ulp difference, well inside margin)
__device__ __forceinline__ unsigned short f2bf(float x) {
  return (unsigned short)((__float_as_uint(x) + 0x8000u) >> 16);
}
// pack two floats -> bf16x2 dword (5 ops)
__device__ __forceinline__ unsigned int pkbf(float lo, float hi) {
  return ((__float_as_uint(lo) + 0x8000u) >> 16) |
         ((__float_as_uint(hi) + 0x8000u) & 0xffff0000u);
}
__device__ __forceinline__ float bflo(unsigned int u) { return __uint_as_float(u << 16); }
__device__ __forceinline__ float bfhi(unsigned int u) { return __uint_as_float(u & 0xffff0000u); }
__device__ __forceinline__ float bfu16(unsigned short us) {
  return __uint_as_float(((unsigned int)us) << 16);
}
__device__ __forceinline__ short8 pack8f(float4 a, float4 b) {
  union { unsigned int u[4]; short8 s; } pk;
  pk.u[0] = pkbf(a.x, a.y);
  pk.u[1] = pkbf(a.z, a.w);
  pk.u[2] = pkbf(b.x, b.y);
  pk.u[3] = pkbf(b.z, b.w);
  return pk.s;
}

// count of set bits in m at lanes strictly below this lane
__device__ __forceinline__ int lane_prefix(unsigned long long m) {
  return __builtin_amdgcn_mbcnt_hi((unsigned)(m >> 32),
         __builtin_amdgcn_mbcnt_lo((unsigned)m, 0));
}

// Full 64-lane bitonic sort, ascending by (v, i) lexicographic.
__device__ __forceinline__ void bitonic64(float& sv, int& si, int lane) {
  #pragma unroll
  for (int k = 2; k <= 64; k <<= 1) {
    #pragma unroll
    for (int j = k >> 1; j > 0; j >>= 1) {
      float ov = __shfl_xor(sv, j);
      int   oi = __shfl_xor(si, j);
      bool up = ((lane & k) == 0);
      bool lower = ((lane & j) == 0);
      bool osm = (ov < sv) || (ov == sv && oi < si);
      bool take = (lower == up) ? osm : !osm;
      if (take) { sv = ov; si = oi; }
    }
  }
}

// exact d2 form shared by threshold, append and merge sites (bit-identical)
__device__ __forceinline__ float d2q(const float4& Q, const float4& C) {
  float dt = fmaf(Q.z, C.z, fmaf(Q.y, C.y, Q.x * C.x));
  return fmaf(-2.0f, dt, Q.w + C.w);
}

// ---- last-block-arrives primitives (grid must be fully co-resident) ----
__device__ __forceinline__ bool arrive_last(int* counter, int nblk) {
  __shared__ int lastf;
  __syncthreads();            // all block stores issued
  __threadfence();            // drained to device scope
  if (threadIdx.x == 0) {
    int old = __hip_atomic_fetch_add(counter, 1, __ATOMIC_ACQ_REL,
                                     __HIP_MEMORY_SCOPE_AGENT);
    lastf = (old == nblk - 1) ? 1 : 0;
  }
  __syncthreads();
  return lastf != 0;
}
__device__ __forceinline__ void set_flag(int* flag) {
  __threadfence();
  __syncthreads();
  if (threadIdx.x == 0)
    __hip_atomic_store(flag, 1, __ATOMIC_RELEASE, __HIP_MEMORY_SCOPE_AGENT);
}
__device__ __forceinline__ void wait_flag(int* flag) {
  if (threadIdx.x == 0) {
    while (__hip_atomic_load(flag, __ATOMIC_ACQUIRE,
                             __HIP_MEMORY_SCOPE_AGENT) == 0)
      __builtin_amdgcn_s_sleep(2);
  }
  __syncthreads();
}

// fin: 256 threads, 256 records of 128 floats -> affine A,B (bn(v)=A*v+B)
__device__ void fin_compute(const float* __restrict__ part,
                            const float* __restrict__ g,
                            const float* __restrict__ b,
                            float* __restrict__ A, float* __restrict__ Bv) {
  __shared__ double fd[256], fd2[256];
  const int t = threadIdx.x, c = t & 63, grp = t >> 6;
  double s = 0.0, s2 = 0.0;
  for (int k = 0; k < 64; ++k) {
    int i = grp * 64 + k;
    s  += part[i * 128 + c];
    s2 += part[i * 128 + 64 + c];
  }
  fd[grp * 64 + c] = s; fd2[grp * 64 + c] = s2;
  __syncthreads();
  if (t < 64) {
    double ts  = fd[t] + fd[64 + t] + fd[128 + t] + fd[192 + t];
    double ts2 = fd2[t] + fd2[64 + t] + fd2[128 + t] + fd2[192 + t];
    double mean = ts / (double)kRows;
    double var = ts2 / (double)kRows - mean * mean;
    float rs = (float)(1.0 / sqrt(var + (double)kEps));
    float Af = g[t] * rs;
    A[t] = Af;
    Bv[t] = b[t] - (float)mean * Af;
  }
  __syncthreads();
}

// ---------------- pack kernel: weight pre-packs + p4 + p-copy + sync zero ----------------
__global__ void pack_kernel(
    const float* __restrict__ aw1, const float* __restrict__ aw2,
    const float* __restrict__ pw2, const float* __restrict__ qw,
    const float* __restrict__ f2w, const float* __restrict__ f1w,
    const float* __restrict__ pin, float* __restrict__ p4o,
    unsigned short* __restrict__ wpak, float* __restrict__ y,
    int* __restrict__ syncbuf) {
  const int id = blockIdx.x * 256 + threadIdx.x;
  if (id < 8) syncbuf[id] = 0;           // counters/flags (re-zeroed per replay)
  // fused p-copy: y[1048576..] = p (196608 floats = 49152 float4)
  if (id < 49152)
    *reinterpret_cast<float4*>(y + 1048576 + 4 * id) =
        *reinterpret_cast<const float4*>(pin + 4 * id);
  if (id < 16384) {
    int j = id & 7, lane = (id >> 3) & 63, rest = id >> 9;
    int mt = rest >> 1, hh = rest & 1;
    wpak[id] = f2bf(aw1[(32 * hh + 8 * (lane >> 4) + j) * 256 + mt * 16 + (lane & 15)]);
    float3 pp = *reinterpret_cast<const float3*>(pin + 3 * id);
    float4 o;
    o.x = pp.x; o.y = pp.y; o.z = pp.z;
    o.w = pp.x * pp.x + pp.y * pp.y + pp.z * pp.z;
    *reinterpret_cast<float4*>(p4o + 4 * id) = o;
  } else if (id < 32768) {
    int i = id - 16384;
    int j = i & 7, lane = (i >> 3) & 63, rest = i >> 9;
    int ct = rest >> 3, f = rest & 7;
    wpak[id] = f2bf(aw2[(32 * f + 8 * (lane >> 4) + j) * 64 + ct * 16 + (lane & 15)]);
  } else if (id < 34816) {
    int i = id - 32768;
    int c = i >> 5, hh = i & 31;
    wpak[id] = f2bf(pw2[hh * 64 + c]);
  } else if (id < 47104) {
    int i = id - 34816;
    int j = i & 7, lane = (i >> 3) & 63, rest = i >> 9;
    int ct = rest >> 1, hh = rest & 1;
    wpak[id] = f2bf(qw[(32 * hh + 8 * (lane >> 4) + j) * 192 + ct * 16 + (lane & 15)]);
  } else if (id < 51200) {
    int i = id - 47104;
    int j = i & 7, lane = (i >> 3) & 63, rest = i >> 9;
    int ct = rest >> 1, hh = rest & 1;
    wpak[id] = f2bf(f2w[(32 * hh + 8 * (lane >> 4) + j) * 64 + ct * 16 + (lane & 15)]);
  } else if (id < 55296) {
    int i = id - 51200;   // fc1_w pack
    int j = i & 7, lane = (i >> 3) & 63, rest = i >> 9;
    int ct = rest >> 1, hh = rest & 1;
    wpak[id] = f2bf(f1w[(32 * hh + 8 * (lane >> 4) + j) * 64 + ct * 16 + (lane & 15)]);
  }
}

// ---------------- fused fc1 + bn1-stats (spin-fin) + qkv; hpre never global ----------------
__global__ __launch_bounds__(256, 4) void fc1_qkv_kernel(
    const float* __restrict__ x, const unsigned short* __restrict__ f1wf,
    const float* __restrict__ fc1_b,
    const float* __restrict__ bn1_g, const float* __restrict__ bn1_b,
    const unsigned short* __restrict__ wqf,
    float* __restrict__ part, float* __restrict__ A1, float* __restrict__ B1,
    int* __restrict__ counter, int* __restrict__ flag,
    float* __restrict__ hout, unsigned short* __restrict__ qkvb) {
  __shared__ float H[64][68];              // fc1 out staging, 17.4 KB (rows 16B-aligned)
  __shared__ float SS[4][4][16], SS2[4][4][16];
  const int t = threadIdx.x;
  const int blk = blockIdx.x;              // 256 blocks
  const int lane = t & 63, wv = t >> 6;
  const int l = lane & 15, q = lane >> 4;
  const int r0 = blk * 64;
  const int row = r0 + wv * 16 + l;
  const f32x4 zero = {0.f, 0.f, 0.f, 0.f};
  // ---- fc1 phase ----
  {
    float4 xa0 = *reinterpret_cast<const float4*>(&x[row * 64 + q * 8]);
    float4 xa1 = *reinterpret_cast<const float4*>(&x[row * 64 + q * 8 + 4]);
    float4 xb0 = *reinterpret_cast<const float4*>(&x[row * 64 + 32 + q * 8]);
    float4 xb1 = *reinterpret_cast<const float4*>(&x[row * 64 + 32 + q * 8 + 4]);
    short8 a0 = pack8f(xa0, xa1), a1 = pack8f(xb0, xb1);
    #pragma unroll
    for (int ct = 0; ct < 4; ++ct) {
      short8 b0 = *reinterpret_cast<const short8*>(&f1wf[(ct * 2 + 0) * 512 + lane * 8]);
      short8 b1 = *reinterpret_cast<const short8*>(&f1wf[(ct * 2 + 1) * 512 + lane * 8]);
      f32x4 acc = __builtin_amdgcn_mfma_f32_16x16x32_bf16(a0, b0, zero, 0, 0, 0);
      acc = __builtin_amdgcn_mfma_f32_16x16x32_bf16(a1, b1, acc, 0, 0, 0);
      const float bc = fc1_b[ct * 16 + l];
      float s = 0.f, s2 = 0.f;
      #pragma unroll
      for (int i = 0; i < 4; ++i) {
        float v = acc[i] + bc;
        H[wv * 16 + q * 4 + i][ct * 16 + l] = v;
        s += v; s2 += v * v;
      }
      s  += __shfl_xor(s, 16, 64);  s  += __shfl_xor(s, 32, 64);
      s2 += __shfl_xor(s2, 16, 64); s2 += __shfl_xor(s2, 32, 64);
      if (q == 0) { SS[wv][ct][l] = s; SS2[wv][ct][l] = s2; }
    }
  }
  __syncthreads();
  if (t < 64) {
    int ct = t >> 4, lc = t & 15;
    part[blk * 128 + t] = SS[0][ct][lc] + SS[1][ct][lc] + SS[2][ct][lc] + SS[3][ct][lc];
    part[blk * 128 + 64 + t] =
        SS2[0][ct][lc] + SS2[1][ct][lc] + SS2[2][ct][lc] + SS2[3][ct][lc];
  }
  // ---- spin-fin: A1/B1 ----
  if (arrive_last(counter, 256)) {
    __threadfence();
    fin_compute(part, bn1_g, bn1_b, A1, B1);
    set_flag(flag);
  } else {
    wait_flag(flag);
  }
  __threadfence();
  // ---- qkv phase (reads H from LDS) ----
  {
    short8 af[2];
    #pragma unroll
    for (int hh = 0; hh < 2; ++hh) {
      const int c0 = 32 * hh + q * 8;
      float4 v0 = *reinterpret_cast<const float4*>(&H[wv * 16 + l][c0]);
      float4 v1 = *reinterpret_cast<const float4*>(&H[wv * 16 + l][c0 + 4]);
      float4 Aa = *reinterpret_cast<const float4*>(&A1[c0]);
      float4 Ab = *reinterpret_cast<const float4*>(&A1[c0 + 4]);
      float4 Ba = *reinterpret_cast<const float4*>(&B1[c0]);
      float4 Bb = *reinterpret_cast<const float4*>(&B1[c0 + 4]);
      v0.x = fmaxf(Aa.x * v0.x + Ba.x, 0.f); v0.y = fmaxf(Aa.y * v0.y + Ba.y, 0.f);
      v0.z = fmaxf(Aa.z * v0.z + Ba.z, 0.f); v0.w = fmaxf(Aa.w * v0.w + Ba.w, 0.f);
      v1.x = fmaxf(Ab.x * v1.x + Bb.x, 0.f); v1.y = fmaxf(Ab.y * v1.y + Bb.y, 0.f);
      v1.z = fmaxf(Ab.z * v1.z + Bb.z, 0.f); v1.w = fmaxf(Ab.w * v1.w + Bb.w, 0.f);
      *reinterpret_cast<float4*>(&hout[row * 64 + c0]) = v0;
      *reinterpret_cast<float4*>(&hout[row * 64 + c0 + 4]) = v1;
      af[hh] = pack8f(v0, v1);
    }
    #pragma unroll
    for (int ct = 0; ct < 12; ++ct) {
      short8 b0 = *reinterpret_cast<const short8*>(&wqf[((ct * 2 + 0) * 64 + lane) * 8]);
      short8 b1 = *reinterpret_cast<const short8*>(&wqf[((ct * 2 + 1) * 64 + lane) * 8]);
      f32x4 acc = __builtin_amdgcn_mfma_f32_16x16x32_bf16(af[0], b0, zero, 0, 0, 0);
      acc = __builtin_amdgcn_mfma_f32_16x16x32_bf16(af[1], b1, acc, 0, 0, 0);
      #pragma unroll
      for (int i = 0; i < 4; ++i)
        qkvb[(r0 + wv * 16 + q * 4 + i) * 192 + ct * 16 + l] = f2bf(acc[i]);
    }
  }
}

// ---------------- fused kNN + MFMA attention v10 (R7-verified, UNCHANGED) ----------------
__global__ __launch_bounds__(256, 4) void knn_attn_kernel(
    const float* __restrict__ p4, const unsigned short* __restrict__ qkv,
    const float* __restrict__ pos_w1, const float* __restrict__ pos_b1,
    const float* __restrict__ pos_b2,
    const float* __restrict__ attn_b1, const float* __restrict__ attn_b2,
    const unsigned short* __restrict__ w1f,
    const unsigned short* __restrict__ w2f,
    const unsigned short* __restrict__ pw2t,
    float* __restrict__ agg) {
  __shared__ unsigned short Ulds[64 * 72];   // [row][c] bf16, stride 72
  __shared__ unsigned short VVb[64 * 72];    // [row][c] bf16, stride 72
  __shared__ float sthr[4];
  __shared__ int   scnt[4];

  const int t = threadIdx.x;
  const int lane = t & 63, w = t >> 6;
  const int l = lane & 15, q = lane >> 4;
  const int work = ((blockIdx.x & 7) << 9) | (blockIdx.x >> 3);  // XCD swizzle
  const int b = work >> 10;
  const int pt_row = work * 4 + w;           // own query row
  const int qrow0 = work * 4;                // block's first query row
  const int base = b * kN;
  const f32x4 zero = {0.f, 0.f, 0.f, 0.f};

  if (t < 4) scnt[t] = 0;

  // block's 4 query points (wave-uniform addresses -> scalar loads)
  const float4 q0f = *reinterpret_cast<const float4*>(p4 + 4 * (qrow0 + 0));
  const float4 q1f = *reinterpret_cast<const float4*>(p4 + 4 * (qrow0 + 1));
  const float4 q2f = *reinterpret_cast<const float4*>(p4 + 4 * (qrow0 + 2));
  const float4 q3f = *reinterpret_cast<const float4*>(p4 + 4 * (qrow0 + 3));
  // own query (for threshold, merge recompute, and attn phase 1b)
  const float4 qp4 = *reinterpret_cast<const float4*>(p4 + 4 * pt_row);
  const float qx = qp4.x, qy = qp4.y, qz = qp4.z, sqq = qp4.w;

  // ---- pass 1: scan own quarter (cands w*1024 + i*64 + lane) for all 4 ----
  unsigned pk0[8], pk1[8], pk2[8], pk3[8];   // bf16x2-trunc d2, 4 queries
  float lmin = kFltMax;
  const int cbase = base + w * 1024;
  #pragma unroll
  for (int g = 0; g < 2; ++g) {
    float4 cc[8];
    #pragma unroll
    for (int jj = 0; jj < 8; ++jj)
      cc[jj] = *reinterpret_cast<const float4*>(p4 + 4 * (cbase + (g * 8 + jj) * 64 + lane));
    #pragma unroll
    for (int jj = 0; jj < 8; ++jj) {
      float dot = fmaf(qz, cc[jj].z, fmaf(qy, cc[jj].y, qx * cc[jj].x));
      lmin = fminf(lmin, fmaf(-2.0f, dot, sqq + cc[jj].w));
    }
    #pragma unroll
    for (int pi = 0; pi < 4; ++pi) {
      const float4 ca = cc[2 * pi], cb = cc[2 * pi + 1];
      pk0[g * 4 + pi] = (__float_as_uint(d2q(q0f, ca)) >> 16) |
                        (__float_as_uint(d2q(q0f, cb)) & 0xffff0000u);
      pk1[g * 4 + pi] = (__float_as_uint(d2q(q1f, ca)) >> 16) |
                        (__float_as_uint(d2q(q1f, cb)) & 0xffff0000u);
      pk2[g * 4 + pi] = (__float_as_uint(d2q(q2f, ca)) >> 16) |
                        (__float_as_uint(d2q(q2f, cb)) & 0xffff0000u);
      pk3[g * 4 + pi] = (__float_as_uint(d2q(q3f, ca)) >> 16) |
                        (__float_as_uint(d2q(q3f, cb)) & 0xffff0000u);
    }
  }
  // own-chunk threshold: 16th smallest lane-min upper-bounds true 16th
  {
    int dummy = lane;
    float lm = lmin;
    bitonic64(lm, dummy, lane);
    float s16 = __shfl(lm, 15);
    if (lane == 0) sthr[w] = s16 + 1e-3f;   // trunc rounds d2 down -> inclusive
  }
  __syncthreads();   // B1: thresholds + zeroed counters visible

  // ---- append: test bf16-down d2 vs thr, aggregated-atomic reservation ----
  {
    auto append_q = [&](const unsigned (&PK)[8], int j) {
      int* listj = reinterpret_cast<int*>(VVb) + j * 576;  // 2304B per query
      const float thrj = sthr[j];
      #pragma unroll
      for (int g = 0; g < 2; ++g) {
        unsigned long long m[8];
        int pc[8];
        #pragma unroll
        for (int c = 0; c < 8; ++c) {
          unsigned pku = PK[g * 4 + (c >> 1)];
          float dv = (c & 1) ? __uint_as_float(pku & 0xffff0000u)
                             : __uint_as_float(pku << 16);
          m[c] = __ballot(dv <= thrj);
          pc[c] = __popcll(m[c]);
        }
        int tot = pc[0] + pc[1] + pc[2] + pc[3] + pc[4] + pc[5] + pc[6] + pc[7];
        int old = 0;
        if (lane == 0) old = atomicAdd(&scnt[j], tot);
        old = __shfl(old, 0);
        int pre = 0;
        #pragma unroll
        for (int c = 0; c < 8; ++c) {
          if ((m[c] >> lane) & 1ull) {
            int pos = old + pre + lane_prefix(m[c]);
            if (pos < kCap) listj[pos] = w * 1024 + (g * 8 + c) * 64 + lane;
          }
          pre += pc[c];
        }
      }
    };
    append_q(pk0, 0);
    append_q(pk1, 1);
    append_q(pk2, 2);
    append_q(pk3, 3);
  }
  __syncthreads();   // B2: all lists + counts final

  // ---- merge own list: exact fp32 re-rank (gathers are L1/L2-hot) ----
  const int n = scnt[w];
  const int* bufi = reinterpret_cast<const int*>(VVb) + w * 576;
  float sv = kFltMax;
  int   si = 0x7fffffff;
  if (n <= kCap) {
    for (int g0 = 0; g0 < n; g0 += 48) {
      float mv; int mi;
      if (lane < 16) { mv = sv; mi = si; }
      else {
        int pos = g0 + (lane - 16);
        if (pos < n) {
          int jj = bufi[pos];
          float4 c = *reinterpret_cast<const float4*>(p4 + 4 * (base + jj));
          mv = d2q(qp4, c);   // bit-identical to threshold site
          mi = jj;
        } else { mv = kFltMax; mi = 0x7fffffff; }
      }
      bitonic64(mv, mi, lane);
      sv = mv; si = mi;
    }
  } else {
    // degenerate-data slow path: full direct rescan, fresh list (no dupes)
    for (int g0 = 0; g0 < kN; g0 += 48) {
      float mv; int mi;
      if (lane < 16) { mv = sv; mi = si; }
      else {
        int j = g0 + (lane - 16);
        if (j < kN) {
          float4 c = *reinterpret_cast<const float4*>(p4 + 4 * (base + j));
          mv = d2q(qp4, c);
          mi = j;
        } else { mv = kFltMax; mi = 0x7fffffff; }
      }
      bitonic64(mv, mi, lane);
      sv = mv; si = mi;
    }
  }

  int idxv = 0;
  if (lane < 16) {
    int o = si;
    if ((unsigned)o >= (unsigned)kN) o = 0;  // safety net: wrong beats fault
    idxv = o;
  }

  // compiler fence: list overlay (int view of VVb) dead; attn writes follow
  asm volatile("" ::: "memory");

  // ---- attention phase (wave-local LDS slices; no barrier needed) ----
  // phase 1a: gather k/v (bf16); U = bf16(q - k); VVb[row][c] = v (raw bf16)
  {
    const int r = lane >> 2, seg = lane & 3;
    const unsigned short* jrow = qkv + (base + __shfl(idxv, r)) * 192;
    const int c0 = seg * 16;
    uint4 k0 = *reinterpret_cast<const uint4*>(jrow + 64 + c0);
    uint4 k1 = *reinterpret_cast<const uint4*>(jrow + 64 + c0 + 8);
    uint4 v0 = *reinterpret_cast<const uint4*>(jrow + 128 + c0);
    uint4 v1 = *reinterpret_cast<const uint4*>(jrow + 128 + c0 + 8);
    uint4 q0 = *reinterpret_cast<const uint4*>(qkv + pt_row * 192 + c0);
    uint4 q1 = *reinterpret_cast<const uint4*>(qkv + pt_row * 192 + c0 + 8);
    auto diff2 = [](unsigned int qu, unsigned int ku) -> unsigned int {
      float lo = bflo(qu) - bflo(ku);
      float hi = bfhi(qu) - bfhi(ku);
      return pkbf(lo, hi);
    };
    uint4 u0, u1;
    u0.x = diff2(q0.x, k0.x); u0.y = diff2(q0.y, k0.y);
    u0.z = diff2(q0.z, k0.z); u0.w = diff2(q0.w, k0.w);
    u1.x = diff2(q1.x, k1.x); u1.y = diff2(q1.y, k1.y);
    u1.z = diff2(q1.z, k1.z); u1.w = diff2(q1.w, k1.w);
    *reinterpret_cast<uint4*>(&Ulds[(w * 16 + r) * 72 + c0]) = u0;
    *reinterpret_cast<uint4*>(&Ulds[(w * 16 + r) * 72 + c0 + 8]) = u1;
    *reinterpret_cast<uint4*>(&VVb[(w * 16 + r) * 72 + c0]) = v0;
    *reinterpret_cast<uint4*>(&VVb[(w * 16 + r) * 72 + c0 + 8]) = v1;
  }
  // phase 1b: pe hidden (3->32) for row l, chunk q*8 — registers only
  short8 pbf;
  {
    const int nj = __shfl(idxv, l);
    const float4 pj4 = *reinterpret_cast<const float4*>(p4 + 4 * (base + nj));
    float rx = qx - pj4.x, ry = qy - pj4.y, rz = qz - pj4.z;
    float hv[8];
    #pragma unroll
    for (int j = 0; j < 8; ++j) {
      int hh = q * 8 + j;
      hv[j] = fmaxf(pos_b1[hh] + rx * pos_w1[hh] + ry * pos_w1[32 + hh] +
                    rz * pos_w1[64 + hh], 0.0f);
    }
    union { unsigned int u[4]; short8 s; } pk;
    #pragma unroll
    for (int ii = 0; ii < 4; ++ii) pk.u[ii] = pkbf(hv[2 * ii], hv[2 * ii + 1]);
    pbf = pk.s;
  }

  // phase 2: pe = pehid @ pos_w2 (transposed MFMA, D[c][row]); RMW U and VVb
  {
    const int urow = (w * 16 + l) * 72;
    #pragma unroll
    for (int mt = 0; mt < 4; ++mt) {
      short8 paf = *reinterpret_cast<const short8*>(&pw2t[(mt * 16 + l) * 32 + q * 8]);
      f32x4 pe = __builtin_amdgcn_mfma_f32_16x16x32_bf16(paf, pbf, zero, 0, 0, 0);
      const int c0 = mt * 16 + q * 4;
      float4 b2v = *reinterpret_cast<const float4*>(&pos_b2[c0]);
      float pe0 = pe[0] + b2v.x, pe1 = pe[1] + b2v.y;
      float pe2 = pe[2] + b2v.z, pe3 = pe[3] + b2v.w;
      uint2 u2 = *reinterpret_cast<uint2*>(&Ulds[urow + c0]);
      uint2 o;
      o.x = pkbf(bflo(u2.x) + pe0, bfhi(u2.x) + pe1);
      o.y = pkbf(bflo(u2.y) + pe2, bfhi(u2.y) + pe3);
      *reinterpret_cast<uint2*>(&Ulds[urow + c0]) = o;
      uint2 v2 = *reinterpret_cast<uint2*>(&VVb[urow + c0]);
      uint2 ov;
      ov.x = pkbf(bflo(v2.x) + pe0, bfhi(v2.x) + pe1);
      ov.y = pkbf(bflo(v2.y) + pe2, bfhi(v2.y) + pe3);
      *reinterpret_cast<uint2*>(&VVb[urow + c0]) = ov;
    }
  }

  // phases 3+4 fused: per f, compute H for mt=2f,2f+1 then immediately
  // repack (2 shfl + 1 select per dword) and run GEMM2's 4 MFMAs.
  {
    f32x4 acc2[4];
    #pragma unroll
    for (int ct = 0; ct < 4; ++ct) acc2[ct] = zero;
    const int urow = (w * 16 + l) * 72;
    short8 ub0 = *reinterpret_cast<const short8*>(&Ulds[urow + q * 8]);
    short8 ub1 = *reinterpret_cast<const short8*>(&Ulds[urow + 32 + q * 8]);
    const int sbase = l + 32 * (q & 1);   // + 16*(d>>1)
    const bool hi_mt = (q >= 2);
    #pragma unroll
    for (int f = 0; f < 8; ++f) {
      unsigned plo2[2], phi2[2];
      #pragma unroll
      for (int s = 0; s < 2; ++s) {
        const int mt = 2 * f + s;
        short8 a0 = *reinterpret_cast<const short8*>(&w1f[(mt * 2 + 0) * 512 + lane * 8]);
        short8 a1 = *reinterpret_cast<const short8*>(&w1f[(mt * 2 + 1) * 512 + lane * 8]);
        f32x4 acc = __builtin_amdgcn_mfma_f32_16x16x32_bf16(a0, ub0, zero, 0, 0, 0);
        acc = __builtin_amdgcn_mfma_f32_16x16x32_bf16(a1, ub1, acc, 0, 0, 0);
        float4 bb = *reinterpret_cast<const float4*>(&attn_b1[mt * 16 + q * 4]);
        plo2[s] = pkbf(fmaxf(acc[0] + bb.x, 0.f), fmaxf(acc[1] + bb.y, 0.f));
        phi2[s] = pkbf(fmaxf(acc[2] + bb.z, 0.f), fmaxf(acc[3] + bb.w, 0.f));
      }
      union { unsigned int u[4]; short8 s; } pk;
      #pragma unroll
      for (int d = 0; d < 4; ++d) {
        const int src = sbase + ((d >> 1) << 4);
        const unsigned int w0 = (d & 1) ? phi2[0] : plo2[0];
        const unsigned int w1v = (d & 1) ? phi2[1] : plo2[1];
        unsigned int va = (unsigned int)__shfl((int)w0, src);
        unsigned int vb = (unsigned int)__shfl((int)w1v, src);
        pk.u[d] = hi_mt ? vb : va;
      }
      short8 afr = pk.s;
      #pragma unroll
      for (int ct = 0; ct < 4; ++ct) {
        short8 bfr = *reinterpret_cast<const short8*>(&w2f[((ct * 8 + f) * 64 + lane) * 8]);
        acc2[ct] = __builtin_amdgcn_mfma_f32_16x16x32_bf16(afr, bfr, acc2[ct], 0, 0, 0);
      }
    }
    #pragma unroll
    for (int ct = 0; ct < 4; ++ct) {
      const int ch = ct * 16 + l;
      const float bv = attn_b2[ch];
      float s0v = acc2[ct][0] + bv, s1v = acc2[ct][1] + bv;
      float s2v = acc2[ct][2] + bv, s3v = acc2[ct][3] + bv;
      float mx = fmaxf(fmaxf(s0v, s1v), fmaxf(s2v, s3v));
      mx = fmaxf(mx, __shfl_xor(mx, 16, 64));
      mx = fmaxf(mx, __shfl_xor(mx, 32, 64));
      float e0 = __expf(s0v - mx), e1 = __expf(s1v - mx);
      float e2 = __expf(s2v - mx), e3 = __expf(s3v - mx);
      float se = e0 + e1 + e2 + e3;
      se += __shfl_xor(se, 16, 64);
      se += __shfl_xor(se, 32, 64);
      const int vbase = (w * 16 + q * 4) * 72 + ch;
      float a = e0 * bfu16(VVb[vbase])       + e1 * bfu16(VVb[vbase + 72]) +
                e2 * bfu16(VVb[vbase + 144]) + e3 * bfu16(VVb[vbase + 216]);
      a += __shfl_xor(a, 16, 64);
      a += __shfl_xor(a, 32, 64);
      if (q == 0) agg[pt_row * 64 + ch] = a / se;
    }
  }
}

// ---------------- fused agg-stats + fc2 + z-stats + bn3 + final; z never global ----------------
__global__ __launch_bounds__(256, 4) void fc2_final_kernel(
    const float* __restrict__ aggp, const float* __restrict__ hres,
    const float* __restrict__ bn2_g, const float* __restrict__ bn2_b,
    const float* __restrict__ bn3_g, const float* __restrict__ bn3_b,
    const unsigned short* __restrict__ fc2f, const float* __restrict__ fc2_b,
    float* __restrict__ partA, float* __restrict__ partZ,
    float* __restrict__ A2, float* __restrict__ B2,
    float* __restrict__ A3, float* __restrict__ B3,
    int* __restrict__ counter2, int* __restrict__ flag2,
    int* __restrict__ counter3, int* __restrict__ flag3,
    float* __restrict__ y) {
  __shared__ float SS[4][4][16], SS2[4][4][16];
  const int t = threadIdx.x, lane = t & 63, wv = t >> 6;
  const int l = lane & 15, q = lane >> 4;
  const int r0 = blockIdx.x * 64;          // 256 blocks
  const int row = r0 + wv * 16 + l;
  const f32x4 zero = {0.f, 0.f, 0.f, 0.f};
  // ---- load agg (serves stats AND fc2 input) + hres early ----
  float4 g0 = *reinterpret_cast<const float4*>(&aggp[row * 64 + q * 8]);
  float4 g1 = *reinterpret_cast<const float4*>(&aggp[row * 64 + q * 8 + 4]);
  float4 g2 = *reinterpret_cast<const float4*>(&aggp[row * 64 + 32 + q * 8]);
  float4 g3 = *reinterpret_cast<const float4*>(&aggp[row * 64 + 32 + q * 8 + 4]);
  float4 r0v = *reinterpret_cast<const float4*>(&hres[row * 64 + q * 8]);
  float4 r1v = *reinterpret_cast<const float4*>(&hres[row * 64 + q * 8 + 4]);
  float4 r2v = *reinterpret_cast<const float4*>(&hres[row * 64 + 32 + q * 8]);
  float4 r3v = *reinterpret_cast<const float4*>(&hres[row * 64 + 32 + q * 8 + 4]);
  // ---- agg column stats: reduce over the 16 rows of each (wv,q) group ----
  {
    float sv[8], s2v[8];
    const float gg[8] = {g0.x, g0.y, g0.z, g0.w, g1.x, g1.y, g1.z, g1.w};
    const float hh2[8] = {g2.x, g2.y, g2.z, g2.w, g3.x, g3.y, g3.z, g3.w};
    #pragma unroll
    for (int j = 0; j < 8; ++j) { sv[j] = gg[j]; s2v[j] = gg[j] * gg[j]; }
    #pragma unroll
    for (int st = 1; st < 16; st <<= 1) {
      #pragma unroll
      for (int j = 0; j < 8; ++j) {
        sv[j]  += __shfl_xor(sv[j], st, 64);
        s2v[j] += __shfl_xor(s2v[j], st, 64);
      }
    }
    // lanes with l==0 hold row-sums for channels q*8+j (lo half)
    if (l == 0) {
      #pragma unroll
      for (int j = 0; j < 8; ++j) {
        SS[wv][0][q * 4 + (j >> 1)] = 0.f;  // placeholder overwritten below
      }
    }
    // store lo-half sums: SS laid out flat as [wv][ch] via [4][4][16] = 64/wave
    if (l == 0) {
      #pragma unroll
      for (int j = 0; j < 8; ++j) {
        (&SS[wv][0][0])[q * 8 + j]  = sv[j];
        (&SS2[wv][0][0])[q * 8 + j] = s2v[j];
      }
    }
    // hi half (channels 32 + q*8+j)
    #pragma unroll
    for (int j = 0; j < 8; ++j) { sv[j] = hh2[j]; s2v[j] = hh2[j] * hh2[j]; }
    #pragma unroll
    for (int st = 1; st < 16; st <<= 1) {
      #pragma unroll
      for (int j = 0; j < 8; ++j) {
        sv[j]  += __shfl_xor(sv[j], st, 64);
        s2v[j] += __shfl_xor(s2v[j], st, 64);
      }
    }
    if (l == 0) {
      #pragma unroll
      for (int j = 0; j < 8; ++j) {
        (&SS[wv][0][0])[32 + q * 8 + j]  = sv[j];
        (&SS2[wv][0][0])[32 + q * 8 + j] = s2v[j];
      }
    }
  }
  __syncthreads();
  if (t < 64) {
    partA[blockIdx.x * 128 + t] = (&SS[0][0][0])[t] + (&SS[1][0][0])[t] +
                                  (&SS[2][0][0])[t] + (&SS[3][0][0])[t];
    partA[blockIdx.x * 128 + 64 + t] = (&SS2[0][0][0])[t] + (&SS2[1][0][0])[t] +
                                       (&SS2[2][0][0])[t] + (&SS2[3][0][0])[t];
  }
  // ---- spin-fin: A2/B2 ----
  if (arrive_last(counter2, 256)) {
    __threadfence();
    fin_compute(partA, bn2_g, bn2_b, A2, B2);
    set_flag(flag2);
  } else {
    wait_flag(flag2);
  }
  __threadfence();
  // ---- fc2 compute (bn2+relu+residual prologue), z kept in registers ----
  float zv[4][4];
  {
    short8 af[2];
    {
      const int c0 = q * 8;
      float4 Aa = *reinterpret_cast<const float4*>(&A2[c0]);
      float4 Ab = *reinterpret_cast<const float4*>(&A2[c0 + 4]);
      float4 Ba = *reinterpret_cast<const float4*>(&B2[c0]);
      float4 Bb = *reinterpret_cast<const float4*>(&B2[c0 + 4]);
      float4 v0 = g0, v1 = g1;
      v0.x = fmaxf(Aa.x * v0.x + Ba.x, 0.f) + r0v.x;
      v0.y = fmaxf(Aa.y * v0.y + Ba.y, 0.f) + r0v.y;
      v0.z = fmaxf(Aa.z * v0.z + Ba.z, 0.f) + r0v.z;
      v0.w = fmaxf(Aa.w * v0.w + Ba.w, 0.f) + r0v.w;
      v1.x = fmaxf(Ab.x * v1.x + Bb.x, 0.f) + r1v.x;
      v1.y = fmaxf(Ab.y * v1.y + Bb.y, 0.f) + r1v.y;
      v1.z = fmaxf(Ab.z * v1.z + Bb.z, 0.f) + r1v.z;
      v1.w = fmaxf(Ab.w * v1.w + Bb.w, 0.f) + r1v.w;
      af[0] = pack8f(v0, v1);
    }
    {
      const int c0 = 32 + q * 8;
      float4 Aa = *reinterpret_cast<const float4*>(&A2[c0]);
      float4 Ab = *reinterpret_cast<const float4*>(&A2[c0 + 4]);
      float4 Ba = *reinterpret_cast<const float4*>(&B2[c0]);
      float4 Bb = *reinterpret_cast<const float4*>(&B2[c0 + 4]);
      float4 v0 = g2, v1 = g3;
      v0.x = fmaxf(Aa.x * v0.x + Ba.x, 0.f) + r2v.x;
      v0.y = fmaxf(Aa.y * v0.y + Ba.y, 0.f) + r2v.y;
      v0.z = fmaxf(Aa.z * v0.z + Ba.z, 0.f) + r2v.z;
      v0.w = fmaxf(Aa.w * v0.w + Ba.w, 0.f) + r2v.w;
      v1.x = fmaxf(Ab.x * v1.x + Bb.x, 0.f) + r3v.x;
      v1.y = fmaxf(Ab.y * v1.y + Bb.y, 0.f) + r3v.y;
      v1.z = fmaxf(Ab.z * v1.z + Bb.z, 0.f) + r3v.z;
      v1.w = fmaxf(Ab.w * v1.w + Bb.w, 0.f) + r3v.w;
      af[1] = pack8f(v0, v1);
    }
    __syncthreads();   // SS reuse fence (stats scratch dead, z-stats next)
    #pragma unroll
    for (int ct = 0; ct < 4; ++ct) {
      short8 b0 = *reinterpret_cast<const short8*>(&fc2f[((ct * 2 + 0) * 64 + lane) * 8]);
      short8 b1 = *reinterpret_cast<const short8*>(&fc2f[((ct * 2 + 1) * 64 + lane) * 8]);
      f32x4 acc = __builtin_amdgcn_mfma_f32_16x16x32_bf16(af[0], b0, zero, 0, 0, 0);
      acc = __builtin_amdgcn_mfma_f32_16x16x32_bf16(af[1], b1, acc, 0, 0, 0);
      const float bc = fc2_b[ct * 16 + l];
      float s = 0.f, s2 = 0.f;
      #pragma unroll
      for (int i = 0; i < 4; ++i) {
        float v = acc[i] + bc;
        zv[ct][i] = v;
        s += v; s2 += v * v;
      }
      s  += __shfl_xor(s, 16, 64);  s  += __shfl_xor(s, 32, 64);
      s2 += __shfl_xor(s2, 16, 64); s2 += __shfl_xor(s2, 32, 64);
      if (q == 0) { SS[wv][ct][l] = s; SS2[wv][ct][l] = s2; }
    }
  }
  __syncthreads();
  if (t < 64) {
    int ct = t >> 4, lc = t & 15;
    partZ[blockIdx.x * 128 + t] =
        SS[0][ct][lc] + SS[1][ct][lc] + SS[2][ct][lc] + SS[3][ct][lc];
    partZ[blockIdx.x * 128 + 64 + t] =
        SS2[0][ct][lc] + SS2[1][ct][lc] + SS2[2][ct][lc] + SS2[3][ct][lc];
  }
  // ---- spin-fin: A3/B3 ----
  if (arrive_last(counter3, 256)) {
    __threadfence();
    fin_compute(partZ, bn3_g, bn3_b, A3, B3);
    set_flag(flag3);
  } else {
    wait_flag(flag3);
  }
  __threadfence();
  // ---- bn3+relu, write y ----
  #pragma unroll
  for (int ct = 0; ct < 4; ++ct) {
    const int ch = ct * 16 + l;
    const float Af = A3[ch], Bf = B3[ch];
    #pragma unroll
    for (int i = 0; i < 4; ++i)
      y[(r0 + wv * 16 + q * 4 + i) * 64 + ch] = fmaxf(Af * zv[ct][i] + Bf, 0.0f);
  }
}

extern "C" void kernel_launch(void* const* d_in, const int* in_sizes, int n_in,
                              void* d_out, int out_size, void* d_ws, size_t ws_size,
                              hipStream_t stream) {
  const float* x       = (const float*)d_in[0];
  const float* p       = (const float*)d_in[1];
  const float* fc1_w   = (const float*)d_in[2];
  const float* fc1_b   = (const float*)d_in[3];
  const float* bn1_g   = (const float*)d_in[4];
  const float* bn1_b   = (const float*)d_in[5];
  const float* qkv_w   = (const float*)d_in[6];
  const float* pos_w1  = (const float*)d_in[7];
  const float* pos_b1  = (const float*)d_in[8];
  const float* pos_w2  = (const float*)d_in[9];
  const float* pos_b2  = (const float*)d_in[10];
  const float* attn_w1 = (const float*)d_in[11];
  const float* attn_b1 = (const float*)d_in[12];
  const float* attn_w2 = (const float*)d_in[13];
  const float* attn_b2 = (const float*)d_in[14];
  const float* bn2_g   = (const float*)d_in[15];
  const float* bn2_b   = (const float*)d_in[16];
  const float* fc2_w   = (const float*)d_in[17];
  const float* fc2_b   = (const float*)d_in[18];
  const float* bn3_g   = (const float*)d_in[19];
  const float* bn3_b   = (const float*)d_in[20];

  float* ws   = (float*)d_ws;
  float* h    = ws;                     // residual, fp32
  unsigned short* qkvb = (unsigned short*)(ws + 1048576);  // bf16 [16384][192]
  float* hpre = ws + 4194304;           // partZ (z stats partials)
  float* aggv = ws + 5242880;           // fc1 stats partials; attn agg
  float* zbuf = ws + 6291456;           // partA (agg stats partials)
  float* st   = ws + 7340032;           // A1,B1,A2,B2,A3,B3 + sync
  float* p4   = ws + 7356800;           // (x,y,z,|p|^2) packed, 16384*4
  unsigned short* wpak = (unsigned short*)(ws + 7618944);
  unsigned short* w1f  = wpak;
  unsigned short* w2f  = wpak + 16384;
  unsigned short* pw2t = wpak + 32768;
  unsigned short* wqf  = wpak + 34816;
  unsigned short* fc2f = wpak + 47104;
  unsigned short* f1wf = wpak + 51200;  // fc1_w packed, 4096 shorts

  float* A1 = st,       *B1 = st + 64;
  float* A2 = st + 128, *B2 = st + 192;
  float* A3 = st + 256, *B3 = st + 320;
  int*  sync = (int*)(st + 384);        // c1,f1,c2,f2,c3,f3 (+pad)
  float* y = (float*)d_out;

  pack_kernel<<<216, 256, 0, stream>>>(attn_w1, attn_w2, pos_w2, qkv_w, fc2_w,
                                       fc1_w, p, p4, wpak, y, sync);
  fc1_qkv_kernel<<<256, 256, 0, stream>>>(x, f1wf, fc1_b, bn1_g, bn1_b, wqf,
                                          aggv, A1, B1, sync + 0, sync + 1,
                                          h, qkvb);
  knn_attn_kernel<<<4096, 256, 0, stream>>>(p4, qkvb, pos_w1, pos_b1, pos_b2,
                                            attn_b1, attn_b2, w1f, w2f, pw2t, aggv);
  fc2_final_kernel<<<256, 256, 0, stream>>>(aggv, h, bn2_g, bn2_b, bn3_g, bn3_b,
                                            fc2f, fc2_b, zbuf, hpre,
                                            A2, B2, A3, B3,
                                            sync + 2, sync + 3, sync + 4, sync + 5,
                                            y);
}

// Round 14
// 245.529 us; speedup vs baseline: 1.9188x; 1.9188x over previous
//
#include <hip/hip_runtime.h>
#include <math.h>

constexpr int kB = 4, kN = 4096, kK = 16;
constexpr int kRows = kB * kN;          // 16384
constexpr float kEps = 1e-5f;
constexpr float kFltMax = 3.402823466e38f;
constexpr int kCap = 240;               // per-query qualifier list (knn)

typedef __attribute__((ext_vector_type(8))) short short8;
typedef __attribute__((ext_vector_type(4))) float f32x4;

// bf16 round-half-up (2 ops vs 4 for RNE; <=1 ulp difference, well inside margin)
__device__ __forceinline__ unsigned short f2bf(float x) {
  return (unsigned short)((__float_as_uint(x) + 0x8000u) >> 16);
}
// pack two floats -> bf16x2 dword (5 ops)
__device__ __forceinline__ unsigned int pkbf(float lo, float hi) {
  return ((__float_as_uint(lo) + 0x8000u) >> 16) |
         ((__float_as_uint(hi) + 0x8000u) & 0xffff0000u);
}
__device__ __forceinline__ float bflo(unsigned int u) { return __uint_as_float(u << 16); }
__device__ __forceinline__ float bfhi(unsigned int u) { return __uint_as_float(u & 0xffff0000u); }
__device__ __forceinline__ float bfu16(unsigned short us) {
  return __uint_as_float(((unsigned int)us) << 16);
}
__device__ __forceinline__ short8 pack8f(float4 a, float4 b) {
  union { unsigned int u[4]; short8 s; } pk;
  pk.u[0] = pkbf(a.x, a.y);
  pk.u[1] = pkbf(a.z, a.w);
  pk.u[2] = pkbf(b.x, b.y);
  pk.u[3] = pkbf(b.z, b.w);
  return pk.s;
}

// count of set bits in m at lanes strictly below this lane
__device__ __forceinline__ int lane_prefix(unsigned long long m) {
  return __builtin_amdgcn_mbcnt_hi((unsigned)(m >> 32),
         __builtin_amdgcn_mbcnt_lo((unsigned)m, 0));
}

// Full 64-lane bitonic sort, ascending by (v, i) lexicographic.
__device__ __forceinline__ void bitonic64(float& sv, int& si, int lane) {
  #pragma unroll
  for (int k = 2; k <= 64; k <<= 1) {
    #pragma unroll
    for (int j = k >> 1; j > 0; j >>= 1) {
      float ov = __shfl_xor(sv, j);
      int   oi = __shfl_xor(si, j);
      bool up = ((lane & k) == 0);
      bool lower = ((lane & j) == 0);
      bool osm = (ov < sv) || (ov == sv && oi < si);
      bool take = (lower == up) ? osm : !osm;
      if (take) { sv = ov; si = oi; }
    }
  }
}

// exact d2 form shared by threshold, append and merge sites (bit-identical)
__device__ __forceinline__ float d2q(const float4& Q, const float4& C) {
  float dt = fmaf(Q.z, C.z, fmaf(Q.y, C.y, Q.x * C.x));
  return fmaf(-2.0f, dt, Q.w + C.w);
}

// ---------------- pack kernel: weight pre-packs + p4 + p-copy (runs once) ----------------
__global__ void pack_kernel(
    const float* __restrict__ aw1, const float* __restrict__ aw2,
    const float* __restrict__ pw2, const float* __restrict__ qw,
    const float* __restrict__ f2w, const float* __restrict__ f1w,
    const float* __restrict__ pin, float* __restrict__ p4o,
    unsigned short* __restrict__ wpak, float* __restrict__ y) {
  const int id = blockIdx.x * 256 + threadIdx.x;
  // fused p-copy: y[1048576..] = p (196608 floats = 49152 float4)
  if (id < 49152)
    *reinterpret_cast<float4*>(y + 1048576 + 4 * id) =
        *reinterpret_cast<const float4*>(pin + 4 * id);
  if (id < 16384) {
    int j = id & 7, lane = (id >> 3) & 63, rest = id >> 9;
    int mt = rest >> 1, hh = rest & 1;
    wpak[id] = f2bf(aw1[(32 * hh + 8 * (lane >> 4) + j) * 256 + mt * 16 + (lane & 15)]);
    // fused p4 pack: (x, y, z, |p|^2) for the knn/attn kernel
    float3 pp = *reinterpret_cast<const float3*>(pin + 3 * id);
    float4 o;
    o.x = pp.x; o.y = pp.y; o.z = pp.z;
    o.w = pp.x * pp.x + pp.y * pp.y + pp.z * pp.z;
    *reinterpret_cast<float4*>(p4o + 4 * id) = o;
  } else if (id < 32768) {
    int i = id - 16384;
    int j = i & 7, lane = (i >> 3) & 63, rest = i >> 9;
    int ct = rest >> 3, f = rest & 7;
    wpak[id] = f2bf(aw2[(32 * f + 8 * (lane >> 4) + j) * 64 + ct * 16 + (lane & 15)]);
  } else if (id < 34816) {
    int i = id - 32768;
    int c = i >> 5, hh = i & 31;
    wpak[id] = f2bf(pw2[hh * 64 + c]);
  } else if (id < 47104) {
    int i = id - 34816;
    int j = i & 7, lane = (i >> 3) & 63, rest = i >> 9;
    int ct = rest >> 1, hh = rest & 1;
    wpak[id] = f2bf(qw[(32 * hh + 8 * (lane >> 4) + j) * 192 + ct * 16 + (lane & 15)]);
  } else if (id < 51200) {
    int i = id - 47104;
    int j = i & 7, lane = (i >> 3) & 63, rest = i >> 9;
    int ct = rest >> 1, hh = rest & 1;
    wpak[id] = f2bf(f2w[(32 * hh + 8 * (lane >> 4) + j) * 64 + ct * 16 + (lane & 15)]);
  } else if (id < 55296) {
    int i = id - 51200;   // fc1_w pack, layout (ct*2+hh)*512 + lane*8 + j
    int j = i & 7, lane = (i >> 3) & 63, rest = i >> 9;
    int ct = rest >> 1, hh = rest & 1;
    wpak[id] = f2bf(f1w[(32 * hh + 8 * (lane >> 4) + j) * 64 + ct * 16 + (lane & 15)]);
  }
}

// ---------------- fc1 (MFMA bf16, 64-row) + fused BN-stats epilogue ----------------
__global__ __launch_bounds__(256) void fc1_conv_kernel(
    const float* __restrict__ x, const unsigned short* __restrict__ f1wf,
    const float* __restrict__ bias, float* __restrict__ out,
    float* __restrict__ part) {
  __shared__ float SS[4][4][16], SS2[4][4][16];   // [wv][ct][l], 2 KB
  const int t = threadIdx.x;
  const int blk = blockIdx.x;              // 256 blocks
  const int lane = t & 63, wv = t >> 6;
  const int l = lane & 15, q = lane >> 4;
  const int r0 = blk * 64;
  const int row = r0 + wv * 16 + l;
  const f32x4 zero = {0.f, 0.f, 0.f, 0.f};
  float4 xa0 = *reinterpret_cast<const float4*>(&x[row * 64 + q * 8]);
  float4 xa1 = *reinterpret_cast<const float4*>(&x[row * 64 + q * 8 + 4]);
  float4 xb0 = *reinterpret_cast<const float4*>(&x[row * 64 + 32 + q * 8]);
  float4 xb1 = *reinterpret_cast<const float4*>(&x[row * 64 + 32 + q * 8 + 4]);
  short8 a0 = pack8f(xa0, xa1), a1 = pack8f(xb0, xb1);
  #pragma unroll
  for (int ct = 0; ct < 4; ++ct) {
    short8 b0 = *reinterpret_cast<const short8*>(&f1wf[(ct * 2 + 0) * 512 + lane * 8]);
    short8 b1 = *reinterpret_cast<const short8*>(&f1wf[(ct * 2 + 1) * 512 + lane * 8]);
    f32x4 acc = __builtin_amdgcn_mfma_f32_16x16x32_bf16(a0, b0, zero, 0, 0, 0);
    acc = __builtin_amdgcn_mfma_f32_16x16x32_bf16(a1, b1, acc, 0, 0, 0);
    const float bc = bias[ct * 16 + l];
    float s = 0.f, s2 = 0.f;
    #pragma unroll
    for (int i = 0; i < 4; ++i) {
      float v = acc[i] + bc;
      out[(r0 + wv * 16 + q * 4 + i) * 64 + ct * 16 + l] = v;
      s += v; s2 += v * v;
    }
    s  += __shfl_xor(s, 16, 64);  s  += __shfl_xor(s, 32, 64);
    s2 += __shfl_xor(s2, 16, 64); s2 += __shfl_xor(s2, 32, 64);
    if (q == 0) { SS[wv][ct][l] = s; SS2[wv][ct][l] = s2; }
  }
  __syncthreads();
  if (t < 64) {
    int ct = t >> 4, lc = t & 15;
    part[blk * 128 + t] = SS[0][ct][lc] + SS[1][ct][lc] + SS[2][ct][lc] + SS[3][ct][lc];
    part[blk * 128 + 64 + t] =
        SS2[0][ct][lc] + SS2[1][ct][lc] + SS2[2][ct][lc] + SS2[3][ct][lc];
  }
}

// ---------------- batchnorm stats (only for agg) ----------------
__global__ void stats_part_kernel(const float* __restrict__ src, float* __restrict__ part) {
  __shared__ float sb[256], sb2[256];
  const int t = threadIdx.x, blk = blockIdx.x;
  const int c = t & 63, rg = t >> 6;
  float s = 0.f, s2 = 0.f;
  for (int r = rg; r < 64; r += 4) {
    float v = src[(blk * 64 + r) * 64 + c];
    s += v; s2 += v * v;
  }
  sb[t] = s; sb2[t] = s2; __syncthreads();
  if (t < 64) {
    float ts  = sb[t] + sb[64 + t] + sb[128 + t] + sb[192 + t];
    float ts2 = sb2[t] + sb2[64 + t] + sb2[128 + t] + sb2[192 + t];
    part[blk * 128 + t] = ts;
    part[blk * 128 + 64 + t] = ts2;
  }
}

// emits affine form: A = g*rs, B = b - mu*g*rs  (bn(v) = A*v + B)
// 1024 threads (16 groups x 64 cols); cnt = number of 128-float records.
__global__ __launch_bounds__(1024) void stats_fin_kernel(
    const float* __restrict__ part,
    const float* __restrict__ g, const float* __restrict__ b,
    float* __restrict__ A, float* __restrict__ Bv, int cnt) {
  __shared__ double ds[1024], ds2[1024];
  const int t = threadIdx.x;            // 1024
  const int c = t & 63, grp = t >> 6;   // 16 groups
  const int per = cnt >> 4;
  double s = 0.0, s2 = 0.0;
  for (int k = 0; k < per; ++k) {
    int i = grp * per + k;
    s  += part[i * 128 + c];
    s2 += part[i * 128 + 64 + c];
  }
  ds[grp * 64 + c] = s; ds2[grp * 64 + c] = s2;
  __syncthreads();
  if (t < 64) {
    double ts = 0.0, ts2 = 0.0;
    #pragma unroll
    for (int gg = 0; gg < 16; ++gg) { ts += ds[gg * 64 + t]; ts2 += ds2[gg * 64 + t]; }
    double mean = ts / (double)kRows;
    double var = ts2 / (double)kRows - mean * mean;
    float rs = (float)(1.0 / sqrt(var + (double)kEps));
    float Af = g[t] * rs;
    A[t] = Af;
    Bv[t] = b[t] - (float)mean * Af;
  }
}

// ---------------- qkv (MFMA, R7-verified shape) fused bn1+relu ----------------
__global__ __launch_bounds__(256) void qkv_bn_kernel(
    const float* __restrict__ hpre, const float* __restrict__ A1,
    const float* __restrict__ B1, const unsigned short* __restrict__ wqf,
    float* __restrict__ hout, unsigned short* __restrict__ out) {
  const int t = threadIdx.x, lane = t & 63, wv = t >> 6;
  const int l = lane & 15, q = lane >> 4;
  const int r0 = blockIdx.x * 64;
  const int row = r0 + wv * 16 + l;
  const f32x4 zero = {0.f, 0.f, 0.f, 0.f};
  short8 af[2];
  #pragma unroll
  for (int hh = 0; hh < 2; ++hh) {
    const int c0 = 32 * hh + q * 8;
    float4 v0 = *reinterpret_cast<const float4*>(&hpre[row * 64 + c0]);
    float4 v1 = *reinterpret_cast<const float4*>(&hpre[row * 64 + c0 + 4]);
    float4 Aa = *reinterpret_cast<const float4*>(&A1[c0]);
    float4 Ab = *reinterpret_cast<const float4*>(&A1[c0 + 4]);
    float4 Ba = *reinterpret_cast<const float4*>(&B1[c0]);
    float4 Bb = *reinterpret_cast<const float4*>(&B1[c0 + 4]);
    v0.x = fmaxf(Aa.x * v0.x + Ba.x, 0.f); v0.y = fmaxf(Aa.y * v0.y + Ba.y, 0.f);
    v0.z = fmaxf(Aa.z * v0.z + Ba.z, 0.f); v0.w = fmaxf(Aa.w * v0.w + Ba.w, 0.f);
    v1.x = fmaxf(Ab.x * v1.x + Bb.x, 0.f); v1.y = fmaxf(Ab.y * v1.y + Bb.y, 0.f);
    v1.z = fmaxf(Ab.z * v1.z + Bb.z, 0.f); v1.w = fmaxf(Ab.w * v1.w + Bb.w, 0.f);
    *reinterpret_cast<float4*>(&hout[row * 64 + c0]) = v0;
    *reinterpret_cast<float4*>(&hout[row * 64 + c0 + 4]) = v1;
    af[hh] = pack8f(v0, v1);
  }
  #pragma unroll
  for (int ct = 0; ct < 12; ++ct) {
    short8 b0 = *reinterpret_cast<const short8*>(&wqf[((ct * 2 + 0) * 64 + lane) * 8]);
    short8 b1 = *reinterpret_cast<const short8*>(&wqf[((ct * 2 + 1) * 64 + lane) * 8]);
    f32x4 acc = __builtin_amdgcn_mfma_f32_16x16x32_bf16(af[0], b0, zero, 0, 0, 0);
    acc = __builtin_amdgcn_mfma_f32_16x16x32_bf16(af[1], b1, acc, 0, 0, 0);
    #pragma unroll
    for (int i = 0; i < 4; ++i)
      out[(r0 + wv * 16 + q * 4 + i) * 192 + ct * 16 + l] = f2bf(acc[i]);
  }
}

// ---------------- fused kNN + MFMA attention v10 (R7-verified, UNCHANGED) ----------------
__global__ __launch_bounds__(256, 4) void knn_attn_kernel(
    const float* __restrict__ p4, const unsigned short* __restrict__ qkv,
    const float* __restrict__ pos_w1, const float* __restrict__ pos_b1,
    const float* __restrict__ pos_b2,
    const float* __restrict__ attn_b1, const float* __restrict__ attn_b2,
    const unsigned short* __restrict__ w1f,
    const unsigned short* __restrict__ w2f,
    const unsigned short* __restrict__ pw2t,
    float* __restrict__ agg) {
  __shared__ unsigned short Ulds[64 * 72];   // [row][c] bf16, stride 72
  __shared__ unsigned short VVb[64 * 72];    // [row][c] bf16, stride 72
  __shared__ float sthr[4];
  __shared__ int   scnt[4];

  const int t = threadIdx.x;
  const int lane = t & 63, w = t >> 6;
  const int l = lane & 15, q = lane >> 4;
  const int work = ((blockIdx.x & 7) << 9) | (blockIdx.x >> 3);  // XCD swizzle
  const int b = work >> 10;
  const int pt_row = work * 4 + w;           // own query row
  const int qrow0 = work * 4;                // block's first query row
  const int base = b * kN;
  const f32x4 zero = {0.f, 0.f, 0.f, 0.f};

  if (t < 4) scnt[t] = 0;

  // block's 4 query points (wave-uniform addresses -> scalar loads)
  const float4 q0f = *reinterpret_cast<const float4*>(p4 + 4 * (qrow0 + 0));
  const float4 q1f = *reinterpret_cast<const float4*>(p4 + 4 * (qrow0 + 1));
  const float4 q2f = *reinterpret_cast<const float4*>(p4 + 4 * (qrow0 + 2));
  const float4 q3f = *reinterpret_cast<const float4*>(p4 + 4 * (qrow0 + 3));
  // own query (for threshold, merge recompute, and attn phase 1b)
  const float4 qp4 = *reinterpret_cast<const float4*>(p4 + 4 * pt_row);
  const float qx = qp4.x, qy = qp4.y, qz = qp4.z, sqq = qp4.w;

  // ---- pass 1: scan own quarter (cands w*1024 + i*64 + lane) for all 4 ----
  unsigned pk0[8], pk1[8], pk2[8], pk3[8];   // bf16x2-trunc d2, 4 queries
  float lmin = kFltMax;
  const int cbase = base + w * 1024;
  #pragma unroll
  for (int g = 0; g < 2; ++g) {
    float4 cc[8];
    #pragma unroll
    for (int jj = 0; jj < 8; ++jj)
      cc[jj] = *reinterpret_cast<const float4*>(p4 + 4 * (cbase + (g * 8 + jj) * 64 + lane));
    #pragma unroll
    for (int jj = 0; jj < 8; ++jj) {
      float dot = fmaf(qz, cc[jj].z, fmaf(qy, cc[jj].y, qx * cc[jj].x));
      lmin = fminf(lmin, fmaf(-2.0f, dot, sqq + cc[jj].w));
    }
    #pragma unroll
    for (int pi = 0; pi < 4; ++pi) {
      const float4 ca = cc[2 * pi], cb = cc[2 * pi + 1];
      pk0[g * 4 + pi] = (__float_as_uint(d2q(q0f, ca)) >> 16) |
                        (__float_as_uint(d2q(q0f, cb)) & 0xffff0000u);
      pk1[g * 4 + pi] = (__float_as_uint(d2q(q1f, ca)) >> 16) |
                        (__float_as_uint(d2q(q1f, cb)) & 0xffff0000u);
      pk2[g * 4 + pi] = (__float_as_uint(d2q(q2f, ca)) >> 16) |
                        (__float_as_uint(d2q(q2f, cb)) & 0xffff0000u);
      pk3[g * 4 + pi] = (__float_as_uint(d2q(q3f, ca)) >> 16) |
                        (__float_as_uint(d2q(q3f, cb)) & 0xffff0000u);
    }
  }
  // own-chunk threshold: 16th smallest lane-min upper-bounds true 16th
  {
    int dummy = lane;
    float lm = lmin;
    bitonic64(lm, dummy, lane);
    float s16 = __shfl(lm, 15);
    if (lane == 0) sthr[w] = s16 + 1e-3f;   // trunc rounds d2 down -> inclusive
  }
  __syncthreads();   // B1: thresholds + zeroed counters visible

  // ---- append: test bf16-down d2 vs thr, aggregated-atomic reservation ----
  {
    auto append_q = [&](const unsigned (&PK)[8], int j) {
      int* listj = reinterpret_cast<int*>(VVb) + j * 576;  // 2304B per query
      const float thrj = sthr[j];
      #pragma unroll
      for (int g = 0; g < 2; ++g) {
        unsigned long long m[8];
        int pc[8];
        #pragma unroll
        for (int c = 0; c < 8; ++c) {
          unsigned pku = PK[g * 4 + (c >> 1)];
          float dv = (c & 1) ? __uint_as_float(pku & 0xffff0000u)
                             : __uint_as_float(pku << 16);
          m[c] = __ballot(dv <= thrj);
          pc[c] = __popcll(m[c]);
        }
        int tot = pc[0] + pc[1] + pc[2] + pc[3] + pc[4] + pc[5] + pc[6] + pc[7];
        int old = 0;
        if (lane == 0) old = atomicAdd(&scnt[j], tot);
        old = __shfl(old, 0);
        int pre = 0;
        #pragma unroll
        for (int c = 0; c < 8; ++c) {
          if ((m[c] >> lane) & 1ull) {
            int pos = old + pre + lane_prefix(m[c]);
            if (pos < kCap) listj[pos] = w * 1024 + (g * 8 + c) * 64 + lane;
          }
          pre += pc[c];
        }
      }
    };
    append_q(pk0, 0);
    append_q(pk1, 1);
    append_q(pk2, 2);
    append_q(pk3, 3);
  }
  __syncthreads();   // B2: all lists + counts final

  // ---- merge own list: exact fp32 re-rank (gathers are L1/L2-hot) ----
  const int n = scnt[w];
  const int* bufi = reinterpret_cast<const int*>(VVb) + w * 576;
  float sv = kFltMax;
  int   si = 0x7fffffff;
  if (n <= kCap) {
    for (int g0 = 0; g0 < n; g0 += 48) {
      float mv; int mi;
      if (lane < 16) { mv = sv; mi = si; }
      else {
        int pos = g0 + (lane - 16);
        if (pos < n) {
          int jj = bufi[pos];
          float4 c = *reinterpret_cast<const float4*>(p4 + 4 * (base + jj));
          mv = d2q(qp4, c);   // bit-identical to threshold site
          mi = jj;
        } else { mv = kFltMax; mi = 0x7fffffff; }
      }
      bitonic64(mv, mi, lane);
      sv = mv; si = mi;
    }
  } else {
    // degenerate-data slow path: full direct rescan, fresh list (no dupes)
    for (int g0 = 0; g0 < kN; g0 += 48) {
      float mv; int mi;
      if (lane < 16) { mv = sv; mi = si; }
      else {
        int j = g0 + (lane - 16);
        if (j < kN) {
          float4 c = *reinterpret_cast<const float4*>(p4 + 4 * (base + j));
          mv = d2q(qp4, c);
          mi = j;
        } else { mv = kFltMax; mi = 0x7fffffff; }
      }
      bitonic64(mv, mi, lane);
      sv = mv; si = mi;
    }
  }

  int idxv = 0;
  if (lane < 16) {
    int o = si;
    if ((unsigned)o >= (unsigned)kN) o = 0;  // safety net: wrong beats fault
    idxv = o;
  }

  // compiler fence: list overlay (int view of VVb) dead; attn writes follow
  asm volatile("" ::: "memory");

  // ---- attention phase (wave-local LDS slices; no barrier needed) ----
  // phase 1a: gather k/v (bf16); U = bf16(q - k); VVb[row][c] = v (raw bf16)
  {
    const int r = lane >> 2, seg = lane & 3;
    const unsigned short* jrow = qkv + (base + __shfl(idxv, r)) * 192;
    const int c0 = seg * 16;
    uint4 k0 = *reinterpret_cast<const uint4*>(jrow + 64 + c0);
    uint4 k1 = *reinterpret_cast<const uint4*>(jrow + 64 + c0 + 8);
    uint4 v0 = *reinterpret_cast<const uint4*>(jrow + 128 + c0);
    uint4 v1 = *reinterpret_cast<const uint4*>(jrow + 128 + c0 + 8);
    uint4 q0 = *reinterpret_cast<const uint4*>(qkv + pt_row * 192 + c0);
    uint4 q1 = *reinterpret_cast<const uint4*>(qkv + pt_row * 192 + c0 + 8);
    auto diff2 = [](unsigned int qu, unsigned int ku) -> unsigned int {
      float lo = bflo(qu) - bflo(ku);
      float hi = bfhi(qu) - bfhi(ku);
      return pkbf(lo, hi);
    };
    uint4 u0, u1;
    u0.x = diff2(q0.x, k0.x); u0.y = diff2(q0.y, k0.y);
    u0.z = diff2(q0.z, k0.z); u0.w = diff2(q0.w, k0.w);
    u1.x = diff2(q1.x, k1.x); u1.y = diff2(q1.y, k1.y);
    u1.z = diff2(q1.z, k1.z); u1.w = diff2(q1.w, k1.w);
    *reinterpret_cast<uint4*>(&Ulds[(w * 16 + r) * 72 + c0]) = u0;
    *reinterpret_cast<uint4*>(&Ulds[(w * 16 + r) * 72 + c0 + 8]) = u1;
    *reinterpret_cast<uint4*>(&VVb[(w * 16 + r) * 72 + c0]) = v0;
    *reinterpret_cast<uint4*>(&VVb[(w * 16 + r) * 72 + c0 + 8]) = v1;
  }
  // phase 1b: pe hidden (3->32) for row l, chunk q*8 — registers only
  short8 pbf;
  {
    const int nj = __shfl(idxv, l);
    const float4 pj4 = *reinterpret_cast<const float4*>(p4 + 4 * (base + nj));
    float rx = qx - pj4.x, ry = qy - pj4.y, rz = qz - pj4.z;
    float hv[8];
    #pragma unroll
    for (int j = 0; j < 8; ++j) {
      int hh = q * 8 + j;
      hv[j] = fmaxf(pos_b1[hh] + rx * pos_w1[hh] + ry * pos_w1[32 + hh] +
                    rz * pos_w1[64 + hh], 0.0f);
    }
    union { unsigned int u[4]; short8 s; } pk;
    #pragma unroll
    for (int ii = 0; ii < 4; ++ii) pk.u[ii] = pkbf(hv[2 * ii], hv[2 * ii + 1]);
    pbf = pk.s;
  }

  // phase 2: pe = pehid @ pos_w2 (transposed MFMA, D[c][row]); RMW U and VVb
  {
    const int urow = (w * 16 + l) * 72;
    #pragma unroll
    for (int mt = 0; mt < 4; ++mt) {
      short8 paf = *reinterpret_cast<const short8*>(&pw2t[(mt * 16 + l) * 32 + q * 8]);
      f32x4 pe = __builtin_amdgcn_mfma_f32_16x16x32_bf16(paf, pbf, zero, 0, 0, 0);
      const int c0 = mt * 16 + q * 4;
      float4 b2v = *reinterpret_cast<const float4*>(&pos_b2[c0]);
      float pe0 = pe[0] + b2v.x, pe1 = pe[1] + b2v.y;
      float pe2 = pe[2] + b2v.z, pe3 = pe[3] + b2v.w;
      uint2 u2 = *reinterpret_cast<uint2*>(&Ulds[urow + c0]);
      uint2 o;
      o.x = pkbf(bflo(u2.x) + pe0, bfhi(u2.x) + pe1);
      o.y = pkbf(bflo(u2.y) + pe2, bfhi(u2.y) + pe3);
      *reinterpret_cast<uint2*>(&Ulds[urow + c0]) = o;
      uint2 v2 = *reinterpret_cast<uint2*>(&VVb[urow + c0]);
      uint2 ov;
      ov.x = pkbf(bflo(v2.x) + pe0, bfhi(v2.x) + pe1);
      ov.y = pkbf(bflo(v2.y) + pe2, bfhi(v2.y) + pe3);
      *reinterpret_cast<uint2*>(&VVb[urow + c0]) = ov;
    }
  }

  // phases 3+4 fused: per f, compute H for mt=2f,2f+1 then immediately
  // repack (2 shfl + 1 select per dword) and run GEMM2's 4 MFMAs.
  {
    f32x4 acc2[4];
    #pragma unroll
    for (int ct = 0; ct < 4; ++ct) acc2[ct] = zero;
    const int urow = (w * 16 + l) * 72;
    short8 ub0 = *reinterpret_cast<const short8*>(&Ulds[urow + q * 8]);
    short8 ub1 = *reinterpret_cast<const short8*>(&Ulds[urow + 32 + q * 8]);
    const int sbase = l + 32 * (q & 1);   // + 16*(d>>1)
    const bool hi_mt = (q >= 2);
    #pragma unroll
    for (int f = 0; f < 8; ++f) {
      unsigned plo2[2], phi2[2];
      #pragma unroll
      for (int s = 0; s < 2; ++s) {
        const int mt = 2 * f + s;
        short8 a0 = *reinterpret_cast<const short8*>(&w1f[(mt * 2 + 0) * 512 + lane * 8]);
        short8 a1 = *reinterpret_cast<const short8*>(&w1f[(mt * 2 + 1) * 512 + lane * 8]);
        f32x4 acc = __builtin_amdgcn_mfma_f32_16x16x32_bf16(a0, ub0, zero, 0, 0, 0);
        acc = __builtin_amdgcn_mfma_f32_16x16x32_bf16(a1, ub1, acc, 0, 0, 0);
        float4 bb = *reinterpret_cast<const float4*>(&attn_b1[mt * 16 + q * 4]);
        plo2[s] = pkbf(fmaxf(acc[0] + bb.x, 0.f), fmaxf(acc[1] + bb.y, 0.f));
        phi2[s] = pkbf(fmaxf(acc[2] + bb.z, 0.f), fmaxf(acc[3] + bb.w, 0.f));
      }
      union { unsigned int u[4]; short8 s; } pk;
      #pragma unroll
      for (int d = 0; d < 4; ++d) {
        const int src = sbase + ((d >> 1) << 4);
        const unsigned int w0 = (d & 1) ? phi2[0] : plo2[0];
        const unsigned int w1v = (d & 1) ? phi2[1] : plo2[1];
        unsigned int va = (unsigned int)__shfl((int)w0, src);
        unsigned int vb = (unsigned int)__shfl((int)w1v, src);
        pk.u[d] = hi_mt ? vb : va;
      }
      short8 afr = pk.s;
      #pragma unroll
      for (int ct = 0; ct < 4; ++ct) {
        short8 bfr = *reinterpret_cast<const short8*>(&w2f[((ct * 8 + f) * 64 + lane) * 8]);
        acc2[ct] = __builtin_amdgcn_mfma_f32_16x16x32_bf16(afr, bfr, acc2[ct], 0, 0, 0);
      }
    }
    #pragma unroll
    for (int ct = 0; ct < 4; ++ct) {
      const int ch = ct * 16 + l;
      const float bv = attn_b2[ch];
      float s0v = acc2[ct][0] + bv, s1v = acc2[ct][1] + bv;
      float s2v = acc2[ct][2] + bv, s3v = acc2[ct][3] + bv;
      float mx = fmaxf(fmaxf(s0v, s1v), fmaxf(s2v, s3v));
      mx = fmaxf(mx, __shfl_xor(mx, 16, 64));
      mx = fmaxf(mx, __shfl_xor(mx, 32, 64));
      float e0 = __expf(s0v - mx), e1 = __expf(s1v - mx);
      float e2 = __expf(s2v - mx), e3 = __expf(s3v - mx);
      float se = e0 + e1 + e2 + e3;
      se += __shfl_xor(se, 16, 64);
      se += __shfl_xor(se, 32, 64);
      const int vbase = (w * 16 + q * 4) * 72 + ch;
      float a = e0 * bfu16(VVb[vbase])       + e1 * bfu16(VVb[vbase + 72]) +
                e2 * bfu16(VVb[vbase + 144]) + e3 * bfu16(VVb[vbase + 216]);
      a += __shfl_xor(a, 16, 64);
      a += __shfl_xor(a, 32, 64);
      if (q == 0) agg[pt_row * 64 + ch] = a / se;
    }
  }
}

// ---------------- fc2 (MFMA, 64-row) + bn2+relu+residual + fused stats epilogue ----------------
__global__ __launch_bounds__(256) void fc2_mfma_kernel(
    const float* __restrict__ aggp, const float* __restrict__ hres,
    const float* __restrict__ A2, const float* __restrict__ B2,
    const unsigned short* __restrict__ fc2f, const float* __restrict__ bias,
    float* __restrict__ z, float* __restrict__ part) {
  __shared__ float SS[4][4][16], SS2[4][4][16];   // [wv][ct][l], 2 KB
  const int t = threadIdx.x, lane = t & 63, wv = t >> 6;
  const int l = lane & 15, q = lane >> 4;
  const int r0 = blockIdx.x * 64;
  const int row = r0 + wv * 16 + l;
  const f32x4 zero = {0.f, 0.f, 0.f, 0.f};
  short8 af[2];
  #pragma unroll
  for (int hh = 0; hh < 2; ++hh) {
    const int c0 = 32 * hh + q * 8;
    float4 v0 = *reinterpret_cast<const float4*>(&aggp[row * 64 + c0]);
    float4 v1 = *reinterpret_cast<const float4*>(&aggp[row * 64 + c0 + 4]);
    float4 r0v = *reinterpret_cast<const float4*>(&hres[row * 64 + c0]);
    float4 r1v = *reinterpret_cast<const float4*>(&hres[row * 64 + c0 + 4]);
    float4 Aa = *reinterpret_cast<const float4*>(&A2[c0]);
    float4 Ab = *reinterpret_cast<const float4*>(&A2[c0 + 4]);
    float4 Ba = *reinterpret_cast<const float4*>(&B2[c0]);
    float4 Bb = *reinterpret_cast<const float4*>(&B2[c0 + 4]);
    v0.x = fmaxf(Aa.x * v0.x + Ba.x, 0.f) + r0v.x;
    v0.y = fmaxf(Aa.y * v0.y + Ba.y, 0.f) + r0v.y;
    v0.z = fmaxf(Aa.z * v0.z + Ba.z, 0.f) + r0v.z;
    v0.w = fmaxf(Aa.w * v0.w + Ba.w, 0.f) + r0v.w;
    v1.x = fmaxf(Ab.x * v1.x + Bb.x, 0.f) + r1v.x;
    v1.y = fmaxf(Ab.y * v1.y + Bb.y, 0.f) + r1v.y;
    v1.z = fmaxf(Ab.z * v1.z + Bb.z, 0.f) + r1v.z;
    v1.w = fmaxf(Ab.w * v1.w + Bb.w, 0.f) + r1v.w;
    af[hh] = pack8f(v0, v1);
  }
  #pragma unroll
  for (int ct = 0; ct < 4; ++ct) {
    short8 b0 = *reinterpret_cast<const short8*>(&fc2f[((ct * 2 + 0) * 64 + lane) * 8]);
    short8 b1 = *reinterpret_cast<const short8*>(&fc2f[((ct * 2 + 1) * 64 + lane) * 8]);
    f32x4 acc = __builtin_amdgcn_mfma_f32_16x16x32_bf16(af[0], b0, zero, 0, 0, 0);
    acc = __builtin_amdgcn_mfma_f32_16x16x32_bf16(af[1], b1, acc, 0, 0, 0);
    const float bc = bias[ct * 16 + l];
    float s = 0.f, s2 = 0.f;
    #pragma unroll
    for (int i = 0; i < 4; ++i) {
      float v = acc[i] + bc;
      z[(r0 + wv * 16 + q * 4 + i) * 64 + ct * 16 + l] = v;
      s += v; s2 += v * v;
    }
    s  += __shfl_xor(s, 16, 64);  s  += __shfl_xor(s, 32, 64);
    s2 += __shfl_xor(s2, 16, 64); s2 += __shfl_xor(s2, 32, 64);
    if (q == 0) { SS[wv][ct][l] = s; SS2[wv][ct][l] = s2; }
  }
  __syncthreads();
  if (t < 64) {
    int ct = t >> 4, lc = t & 15;
    part[blockIdx.x * 128 + t] =
        SS[0][ct][lc] + SS[1][ct][lc] + SS[2][ct][lc] + SS[3][ct][lc];
    part[blockIdx.x * 128 + 64 + t] =
        SS2[0][ct][lc] + SS2[1][ct][lc] + SS2[2][ct][lc] + SS2[3][ct][lc];
  }
}

// ---------------- final bn3+relu, float4-vectorized (p-copy in pack) ----------------
__global__ void final_kernel(const float* __restrict__ z, const float* __restrict__ A3,
                             const float* __restrict__ B3, float* __restrict__ y) {
  const int i4 = (blockIdx.x * 256 + threadIdx.x) * 4;   // 1024 blocks
  const int c = i4 & 63;
  float4 zv = *reinterpret_cast<const float4*>(z + i4);
  float4 Av = *reinterpret_cast<const float4*>(A3 + c);
  float4 Bv = *reinterpret_cast<const float4*>(B3 + c);
  float4 o;
  o.x = fmaxf(Av.x * zv.x + Bv.x, 0.0f);
  o.y = fmaxf(Av.y * zv.y + Bv.y, 0.0f);
  o.z = fmaxf(Av.z * zv.z + Bv.z, 0.0f);
  o.w = fmaxf(Av.w * zv.w + Bv.w, 0.0f);
  *reinterpret_cast<float4*>(y + i4) = o;
}

extern "C" void kernel_launch(void* const* d_in, const int* in_sizes, int n_in,
                              void* d_out, int out_size, void* d_ws, size_t ws_size,
                              hipStream_t stream) {
  const float* x       = (const float*)d_in[0];
  const float* p       = (const float*)d_in[1];
  const float* fc1_w   = (const float*)d_in[2];
  const float* fc1_b   = (const float*)d_in[3];
  const float* bn1_g   = (const float*)d_in[4];
  const float* bn1_b   = (const float*)d_in[5];
  const float* qkv_w   = (const float*)d_in[6];
  const float* pos_w1  = (const float*)d_in[7];
  const float* pos_b1  = (const float*)d_in[8];
  const float* pos_w2  = (const float*)d_in[9];
  const float* pos_b2  = (const float*)d_in[10];
  const float* attn_w1 = (const float*)d_in[11];
  const float* attn_b1 = (const float*)d_in[12];
  const float* attn_w2 = (const float*)d_in[13];
  const float* attn_b2 = (const float*)d_in[14];
  const float* bn2_g   = (const float*)d_in[15];
  const float* bn2_b   = (const float*)d_in[16];
  const float* fc2_w   = (const float*)d_in[17];
  const float* fc2_b   = (const float*)d_in[18];
  const float* bn3_g   = (const float*)d_in[19];
  const float* bn3_b   = (const float*)d_in[20];

  float* ws   = (float*)d_ws;
  float* h    = ws;                     // residual, fp32
  unsigned short* qkvb = (unsigned short*)(ws + 1048576);  // bf16 [16384][192]
  float* hpre = ws + 4194304;           // fc1 out; later fc2 stats partials
  float* aggv = ws + 5242880;           // fc1 stats partials; attn agg
  float* z    = ws + 6291456;           // agg stats partials; fc2 out
  float* st   = ws + 7340032;           // A1,B1,A2,B2,A3,B3
  float* p4   = ws + 7356800;           // (x,y,z,|p|^2) packed, 16384*4
  unsigned short* wpak = (unsigned short*)(ws + 7618944);
  unsigned short* w1f  = wpak;
  unsigned short* w2f  = wpak + 16384;
  unsigned short* pw2t = wpak + 32768;
  unsigned short* wqf  = wpak + 34816;
  unsigned short* fc2f = wpak + 47104;
  unsigned short* f1wf = wpak + 51200;  // fc1_w packed, 4096 shorts

  float* A1 = st,       *B1 = st + 64;
  float* A2 = st + 128, *B2 = st + 192;
  float* A3 = st + 256, *B3 = st + 320;
  float* y = (float*)d_out;

  pack_kernel<<<216, 256, 0, stream>>>(attn_w1, attn_w2, pos_w2, qkv_w, fc2_w,
                                       fc1_w, p, p4, wpak, y);
  fc1_conv_kernel<<<256, 256, 0, stream>>>(x, f1wf, fc1_b, hpre, aggv);
  stats_fin_kernel<<<1, 1024, 0, stream>>>(aggv, bn1_g, bn1_b, A1, B1, 256);
  qkv_bn_kernel<<<256, 256, 0, stream>>>(hpre, A1, B1, wqf, h, qkvb);
  knn_attn_kernel<<<4096, 256, 0, stream>>>(p4, qkvb, pos_w1, pos_b1, pos_b2,
                                            attn_b1, attn_b2, w1f, w2f, pw2t, aggv);
  stats_part_kernel<<<256, 256, 0, stream>>>(aggv, z);
  stats_fin_kernel<<<1, 1024, 0, stream>>>(z, bn2_g, bn2_b, A2, B2, 256);
  fc2_mfma_kernel<<<256, 256, 0, stream>>>(aggv, h, A2, B2, fc2f, fc2_b, z, hpre);
  stats_fin_kernel<<<1, 1024, 0, stream>>>(hpre, bn3_g, bn3_b, A3, B3, 256);
  final_kernel<<<1024, 256, 0, stream>>>(z, A3, B3, y);
}

// Round 15
// 233.941 us; speedup vs baseline: 2.0139x; 1.0495x over previous
//
#include <hip/hip_runtime.h>
#include <math.h>

constexpr int kB = 4, kN = 4096, kK = 16;
constexpr int kRows = kB * kN;          // 16384
constexpr float kEps = 1e-5f;
constexpr float kFltMax = 3.402823466e38f;
constexpr int kCap = 240;               // per-query qualifier list (knn)

typedef __attribute__((ext_vector_type(8))) short short8;
typedef __attribute__((ext_vector_type(4))) float f32x4;

// bf16 round-half-up (2 ops vs 4 for RNE; <=1 ulp difference, well inside margin)
__device__ __forceinline__ unsigned short f2bf(float x) {
  return (unsigned short)((__float_as_uint(x) + 0x8000u) >> 16);
}
// pack two floats -> bf16x2 dword (5 ops)
__device__ __forceinline__ unsigned int pkbf(float lo, float hi) {
  return ((__float_as_uint(lo) + 0x8000u) >> 16) |
         ((__float_as_uint(hi) + 0x8000u) & 0xffff0000u);
}
__device__ __forceinline__ float bflo(unsigned int u) { return __uint_as_float(u << 16); }
__device__ __forceinline__ float bfhi(unsigned int u) { return __uint_as_float(u & 0xffff0000u); }
__device__ __forceinline__ float bfu16(unsigned short us) {
  return __uint_as_float(((unsigned int)us) << 16);
}
__device__ __forceinline__ short8 pack8f(float4 a, float4 b) {
  union { unsigned int u[4]; short8 s; } pk;
  pk.u[0] = pkbf(a.x, a.y);
  pk.u[1] = pkbf(a.z, a.w);
  pk.u[2] = pkbf(b.x, b.y);
  pk.u[3] = pkbf(b.z, b.w);
  return pk.s;
}

// count of set bits in m at lanes strictly below this lane
__device__ __forceinline__ int lane_prefix(unsigned long long m) {
  return __builtin_amdgcn_mbcnt_hi((unsigned)(m >> 32),
         __builtin_amdgcn_mbcnt_lo((unsigned)m, 0));
}

// Full 64-lane bitonic sort, ascending by (v, i) lexicographic.
__device__ __forceinline__ void bitonic64(float& sv, int& si, int lane) {
  #pragma unroll
  for (int k = 2; k <= 64; k <<= 1) {
    #pragma unroll
    for (int j = k >> 1; j > 0; j >>= 1) {
      float ov = __shfl_xor(sv, j);
      int   oi = __shfl_xor(si, j);
      bool up = ((lane & k) == 0);
      bool lower = ((lane & j) == 0);
      bool osm = (ov < sv) || (ov == sv && oi < si);
      bool take = (lower == up) ? osm : !osm;
      if (take) { sv = ov; si = oi; }
    }
  }
}

// exact d2 form shared by threshold, append and merge sites (bit-identical)
__device__ __forceinline__ float d2q(const float4& Q, const float4& C) {
  float dt = fmaf(Q.z, C.z, fmaf(Q.y, C.y, Q.x * C.x));
  return fmaf(-2.0f, dt, Q.w + C.w);
}

// ---------------- pack kernel: weight pre-packs + p4 + p-copy (runs once) ----------------
__global__ void pack_kernel(
    const float* __restrict__ aw1, const float* __restrict__ aw2,
    const float* __restrict__ pw2, const float* __restrict__ qw,
    const float* __restrict__ f2w, const float* __restrict__ f1w,
    const float* __restrict__ pin, float* __restrict__ p4o,
    unsigned short* __restrict__ wpak, float* __restrict__ y) {
  const int id = blockIdx.x * 256 + threadIdx.x;
  // fused p-copy: y[1048576..] = p (196608 floats = 49152 float4)
  if (id < 49152)
    *reinterpret_cast<float4*>(y + 1048576 + 4 * id) =
        *reinterpret_cast<const float4*>(pin + 4 * id);
  if (id < 16384) {
    int j = id & 7, lane = (id >> 3) & 63, rest = id >> 9;
    int mt = rest >> 1, hh = rest & 1;
    wpak[id] = f2bf(aw1[(32 * hh + 8 * (lane >> 4) + j) * 256 + mt * 16 + (lane & 15)]);
    // fused p4 pack: (x, y, z, |p|^2) for the knn/attn kernel
    float3 pp = *reinterpret_cast<const float3*>(pin + 3 * id);
    float4 o;
    o.x = pp.x; o.y = pp.y; o.z = pp.z;
    o.w = pp.x * pp.x + pp.y * pp.y + pp.z * pp.z;
    *reinterpret_cast<float4*>(p4o + 4 * id) = o;
  } else if (id < 32768) {
    int i = id - 16384;
    int j = i & 7, lane = (i >> 3) & 63, rest = i >> 9;
    int ct = rest >> 3, f = rest & 7;
    wpak[id] = f2bf(aw2[(32 * f + 8 * (lane >> 4) + j) * 64 + ct * 16 + (lane & 15)]);
  } else if (id < 34816) {
    int i = id - 32768;
    int c = i >> 5, hh = i & 31;
    wpak[id] = f2bf(pw2[hh * 64 + c]);
  } else if (id < 47104) {
    int i = id - 34816;
    int j = i & 7, lane = (i >> 3) & 63, rest = i >> 9;
    int ct = rest >> 1, hh = rest & 1;
    wpak[id] = f2bf(qw[(32 * hh + 8 * (lane >> 4) + j) * 192 + ct * 16 + (lane & 15)]);
  } else if (id < 51200) {
    int i = id - 47104;
    int j = i & 7, lane = (i >> 3) & 63, rest = i >> 9;
    int ct = rest >> 1, hh = rest & 1;
    wpak[id] = f2bf(f2w[(32 * hh + 8 * (lane >> 4) + j) * 64 + ct * 16 + (lane & 15)]);
  } else if (id < 55296) {
    int i = id - 51200;   // fc1_w pack, layout (ct*2+hh)*512 + lane*8 + j
    int j = i & 7, lane = (i >> 3) & 63, rest = i >> 9;
    int ct = rest >> 1, hh = rest & 1;
    wpak[id] = f2bf(f1w[(32 * hh + 8 * (lane >> 4) + j) * 64 + ct * 16 + (lane & 15)]);
  }
}

// ---------------- fc1 (MFMA bf16, 64-row) + fused BN-stats epilogue ----------------
__global__ __launch_bounds__(256) void fc1_conv_kernel(
    const float* __restrict__ x, const unsigned short* __restrict__ f1wf,
    const float* __restrict__ bias, float* __restrict__ out,
    float* __restrict__ part) {
  __shared__ float SS[4][4][16], SS2[4][4][16];   // [wv][ct][l], 2 KB
  const int t = threadIdx.x;
  const int blk = blockIdx.x;              // 256 blocks
  const int lane = t & 63, wv = t >> 6;
  const int l = lane & 15, q = lane >> 4;
  const int r0 = blk * 64;
  const int row = r0 + wv * 16 + l;
  const f32x4 zero = {0.f, 0.f, 0.f, 0.f};
  float4 xa0 = *reinterpret_cast<const float4*>(&x[row * 64 + q * 8]);
  float4 xa1 = *reinterpret_cast<const float4*>(&x[row * 64 + q * 8 + 4]);
  float4 xb0 = *reinterpret_cast<const float4*>(&x[row * 64 + 32 + q * 8]);
  float4 xb1 = *reinterpret_cast<const float4*>(&x[row * 64 + 32 + q * 8 + 4]);
  short8 a0 = pack8f(xa0, xa1), a1 = pack8f(xb0, xb1);
  #pragma unroll
  for (int ct = 0; ct < 4; ++ct) {
    short8 b0 = *reinterpret_cast<const short8*>(&f1wf[(ct * 2 + 0) * 512 + lane * 8]);
    short8 b1 = *reinterpret_cast<const short8*>(&f1wf[(ct * 2 + 1) * 512 + lane * 8]);
    f32x4 acc = __builtin_amdgcn_mfma_f32_16x16x32_bf16(a0, b0, zero, 0, 0, 0);
    acc = __builtin_amdgcn_mfma_f32_16x16x32_bf16(a1, b1, acc, 0, 0, 0);
    const float bc = bias[ct * 16 + l];
    float s = 0.f, s2 = 0.f;
    #pragma unroll
    for (int i = 0; i < 4; ++i) {
      float v = acc[i] + bc;
      out[(r0 + wv * 16 + q * 4 + i) * 64 + ct * 16 + l] = v;
      s += v; s2 += v * v;
    }
    s  += __shfl_xor(s, 16, 64);  s  += __shfl_xor(s, 32, 64);
    s2 += __shfl_xor(s2, 16, 64); s2 += __shfl_xor(s2, 32, 64);
    if (q == 0) { SS[wv][ct][l] = s; SS2[wv][ct][l] = s2; }
  }
  __syncthreads();
  if (t < 64) {
    int ct = t >> 4, lc = t & 15;
    part[blk * 128 + t] = SS[0][ct][lc] + SS[1][ct][lc] + SS[2][ct][lc] + SS[3][ct][lc];
    part[blk * 128 + 64 + t] =
        SS2[0][ct][lc] + SS2[1][ct][lc] + SS2[2][ct][lc] + SS2[3][ct][lc];
  }
}

// ---------------- batchnorm stats (only for agg) ----------------
__global__ void stats_part_kernel(const float* __restrict__ src, float* __restrict__ part) {
  __shared__ float sb[256], sb2[256];
  const int t = threadIdx.x, blk = blockIdx.x;
  const int c = t & 63, rg = t >> 6;
  float s = 0.f, s2 = 0.f;
  for (int r = rg; r < 64; r += 4) {
    float v = src[(blk * 64 + r) * 64 + c];
    s += v; s2 += v * v;
  }
  sb[t] = s; sb2[t] = s2; __syncthreads();
  if (t < 64) {
    float ts  = sb[t] + sb[64 + t] + sb[128 + t] + sb[192 + t];
    float ts2 = sb2[t] + sb2[64 + t] + sb2[128 + t] + sb2[192 + t];
    part[blk * 128 + t] = ts;
    part[blk * 128 + 64 + t] = ts2;
  }
}

// emits affine form: A = g*rs, B = b - mu*g*rs  (bn(v) = A*v + B)
// 1024 threads (16 groups x 64 cols); cnt = number of 128-float records.
__global__ __launch_bounds__(1024) void stats_fin_kernel(
    const float* __restrict__ part,
    const float* __restrict__ g, const float* __restrict__ b,
    float* __restrict__ A, float* __restrict__ Bv, int cnt) {
  __shared__ double ds[1024], ds2[1024];
  const int t = threadIdx.x;            // 1024
  const int c = t & 63, grp = t >> 6;   // 16 groups
  const int per = cnt >> 4;
  double s = 0.0, s2 = 0.0;
  for (int k = 0; k < per; ++k) {
    int i = grp * per + k;
    s  += part[i * 128 + c];
    s2 += part[i * 128 + 64 + c];
  }
  ds[grp * 64 + c] = s; ds2[grp * 64 + c] = s2;
  __syncthreads();
  if (t < 64) {
    double ts = 0.0, ts2 = 0.0;
    #pragma unroll
    for (int gg = 0; gg < 16; ++gg) { ts += ds[gg * 64 + t]; ts2 += ds2[gg * 64 + t]; }
    double mean = ts / (double)kRows;
    double var = ts2 / (double)kRows - mean * mean;
    float rs = (float)(1.0 / sqrt(var + (double)kEps));
    float Af = g[t] * rs;
    A[t] = Af;
    Bv[t] = b[t] - (float)mean * Af;
  }
}

// ---------------- qkv (MFMA, R7-verified shape) fused bn1+relu ----------------
__global__ __launch_bounds__(256) void qkv_bn_kernel(
    const float* __restrict__ hpre, const float* __restrict__ A1,
    const float* __restrict__ B1, const unsigned short* __restrict__ wqf,
    float* __restrict__ hout, unsigned short* __restrict__ out) {
  const int t = threadIdx.x, lane = t & 63, wv = t >> 6;
  const int l = lane & 15, q = lane >> 4;
  const int r0 = blockIdx.x * 64;
  const int row = r0 + wv * 16 + l;
  const f32x4 zero = {0.f, 0.f, 0.f, 0.f};
  short8 af[2];
  #pragma unroll
  for (int hh = 0; hh < 2; ++hh) {
    const int c0 = 32 * hh + q * 8;
    float4 v0 = *reinterpret_cast<const float4*>(&hpre[row * 64 + c0]);
    float4 v1 = *reinterpret_cast<const float4*>(&hpre[row * 64 + c0 + 4]);
    float4 Aa = *reinterpret_cast<const float4*>(&A1[c0]);
    float4 Ab = *reinterpret_cast<const float4*>(&A1[c0 + 4]);
    float4 Ba = *reinterpret_cast<const float4*>(&B1[c0]);
    float4 Bb = *reinterpret_cast<const float4*>(&B1[c0 + 4]);
    v0.x = fmaxf(Aa.x * v0.x + Ba.x, 0.f); v0.y = fmaxf(Aa.y * v0.y + Ba.y, 0.f);
    v0.z = fmaxf(Aa.z * v0.z + Ba.z, 0.f); v0.w = fmaxf(Aa.w * v0.w + Ba.w, 0.f);
    v1.x = fmaxf(Ab.x * v1.x + Bb.x, 0.f); v1.y = fmaxf(Ab.y * v1.y + Bb.y, 0.f);
    v1.z = fmaxf(Ab.z * v1.z + Bb.z, 0.f); v1.w = fmaxf(Ab.w * v1.w + Bb.w, 0.f);
    *reinterpret_cast<float4*>(&hout[row * 64 + c0]) = v0;
    *reinterpret_cast<float4*>(&hout[row * 64 + c0 + 4]) = v1;
    af[hh] = pack8f(v0, v1);
  }
  #pragma unroll
  for (int ct = 0; ct < 12; ++ct) {
    short8 b0 = *reinterpret_cast<const short8*>(&wqf[((ct * 2 + 0) * 64 + lane) * 8]);
    short8 b1 = *reinterpret_cast<const short8*>(&wqf[((ct * 2 + 1) * 64 + lane) * 8]);
    f32x4 acc = __builtin_amdgcn_mfma_f32_16x16x32_bf16(af[0], b0, zero, 0, 0, 0);
    acc = __builtin_amdgcn_mfma_f32_16x16x32_bf16(af[1], b1, acc, 0, 0, 0);
    #pragma unroll
    for (int i = 0; i < 4; ++i)
      out[(r0 + wv * 16 + q * 4 + i) * 192 + ct * 16 + l] = f2bf(acc[i]);
  }
}

// ---------------- fused kNN + MFMA attention v11 ----------------
// v10 + (a) cross-wave lane-min combine (v7 idea, retried under the pinned
// (256,4) register budget that fixes the spills v7 hit): threshold drops
// from ~64th to ~20th order statistic -> append writes ~3x fewer, merge is
// ONE bitonic pass; all threshold/merge sites stay bit-identical fp32 d2q.
// (b) s_setprio(1) around the phase-3+4 MFMA cluster (blocks run phase-
// independent -> scheduler can favor MFMA waves, cf. guide m191 attn case).
__global__ __launch_bounds__(256, 4) void knn_attn_kernel(
    const float* __restrict__ p4, const unsigned short* __restrict__ qkv,
    const float* __restrict__ pos_w1, const float* __restrict__ pos_b1,
    const float* __restrict__ pos_b2,
    const float* __restrict__ attn_b1, const float* __restrict__ attn_b2,
    const unsigned short* __restrict__ w1f,
    const unsigned short* __restrict__ w2f,
    const unsigned short* __restrict__ pw2t,
    float* __restrict__ agg) {
  __shared__ unsigned short Ulds[64 * 72];   // [row][c] bf16, stride 72
  __shared__ unsigned short VVb[64 * 72];    // [row][c] bf16, stride 72
  __shared__ float sthr[4];
  __shared__ int   scnt[4];

  const int t = threadIdx.x;
  const int lane = t & 63, w = t >> 6;
  const int l = lane & 15, q = lane >> 4;
  const int work = ((blockIdx.x & 7) << 9) | (blockIdx.x >> 3);  // XCD swizzle
  const int b = work >> 10;
  const int pt_row = work * 4 + w;           // own query row
  const int qrow0 = work * 4;                // block's first query row
  const int base = b * kN;
  const f32x4 zero = {0.f, 0.f, 0.f, 0.f};

  if (t < 4) scnt[t] = 0;

  // block's 4 query points (wave-uniform addresses -> scalar loads)
  const float4 q0f = *reinterpret_cast<const float4*>(p4 + 4 * (qrow0 + 0));
  const float4 q1f = *reinterpret_cast<const float4*>(p4 + 4 * (qrow0 + 1));
  const float4 q2f = *reinterpret_cast<const float4*>(p4 + 4 * (qrow0 + 2));
  const float4 q3f = *reinterpret_cast<const float4*>(p4 + 4 * (qrow0 + 3));
  // own query (for merge recompute and attn phase 1b)
  const float4 qp4 = *reinterpret_cast<const float4*>(p4 + 4 * pt_row);
  const float qx = qp4.x, qy = qp4.y, qz = qp4.z;

  // ---- pass 1: scan own quarter for all 4 queries; track 4 lane-mins ----
  unsigned pk0[8], pk1[8], pk2[8], pk3[8];   // bf16x2-trunc d2, 4 queries
  float lm0 = kFltMax, lm1 = kFltMax, lm2 = kFltMax, lm3 = kFltMax;
  const int cbase = base + w * 1024;
  #pragma unroll
  for (int g = 0; g < 2; ++g) {
    float4 cc[8];
    #pragma unroll
    for (int jj = 0; jj < 8; ++jj)
      cc[jj] = *reinterpret_cast<const float4*>(p4 + 4 * (cbase + (g * 8 + jj) * 64 + lane));
    #pragma unroll
    for (int pi = 0; pi < 4; ++pi) {
      const float4 ca = cc[2 * pi], cb = cc[2 * pi + 1];
      float d0a = d2q(q0f, ca), d0b = d2q(q0f, cb);
      float d1a = d2q(q1f, ca), d1b = d2q(q1f, cb);
      float d2a = d2q(q2f, ca), d2b = d2q(q2f, cb);
      float d3a = d2q(q3f, ca), d3b = d2q(q3f, cb);
      lm0 = fminf(lm0, fminf(d0a, d0b));
      lm1 = fminf(lm1, fminf(d1a, d1b));
      lm2 = fminf(lm2, fminf(d2a, d2b));
      lm3 = fminf(lm3, fminf(d3a, d3b));
      pk0[g * 4 + pi] = (__float_as_uint(d0a) >> 16) | (__float_as_uint(d0b) & 0xffff0000u);
      pk1[g * 4 + pi] = (__float_as_uint(d1a) >> 16) | (__float_as_uint(d1b) & 0xffff0000u);
      pk2[g * 4 + pi] = (__float_as_uint(d2a) >> 16) | (__float_as_uint(d2b) & 0xffff0000u);
      pk3[g * 4 + pi] = (__float_as_uint(d3a) >> 16) | (__float_as_uint(d3b) & 0xffff0000u);
    }
  }
  // publish lane-mins to Ulds overlay (dead until attn phase 1a)
  {
    float* lmbuf = reinterpret_cast<float*>(Ulds);
    lmbuf[w * 256 + 0 * 64 + lane] = lm0;
    lmbuf[w * 256 + 1 * 64 + lane] = lm1;
    lmbuf[w * 256 + 2 * 64 + lane] = lm2;
    lmbuf[w * 256 + 3 * 64 + lane] = lm3;
  }
  __syncthreads();   // B0: lane-mins visible
  // combined lane-min over all 4 quarters for OWN query -> tight threshold
  {
    const float* lmbuf = reinterpret_cast<const float*>(Ulds);
    float cv = fminf(fminf(lmbuf[0 * 256 + w * 64 + lane],
                           lmbuf[1 * 256 + w * 64 + lane]),
                     fminf(lmbuf[2 * 256 + w * 64 + lane],
                           lmbuf[3 * 256 + w * 64 + lane]));
    int dummy = lane;
    bitonic64(cv, dummy, lane);
    float s16 = __shfl(cv, 15);   // >=16 cands (one per lane) at or below
    if (lane == 0) sthr[w] = s16 + 1e-3f;  // sites bit-identical -> pure safety
  }
  __syncthreads();   // B1: thresholds + zeroed counters visible

  // ---- append: test bf16-down d2 vs thr, aggregated-atomic reservation ----
  {
    auto append_q = [&](const unsigned (&PK)[8], int j) {
      int* listj = reinterpret_cast<int*>(VVb) + j * 576;  // 2304B per query
      const float thrj = sthr[j];
      #pragma unroll
      for (int g = 0; g < 2; ++g) {
        unsigned long long m[8];
        int pc[8];
        #pragma unroll
        for (int c = 0; c < 8; ++c) {
          unsigned pku = PK[g * 4 + (c >> 1)];
          float dv = (c & 1) ? __uint_as_float(pku & 0xffff0000u)
                             : __uint_as_float(pku << 16);
          m[c] = __ballot(dv <= thrj);
          pc[c] = __popcll(m[c]);
        }
        int tot = pc[0] + pc[1] + pc[2] + pc[3] + pc[4] + pc[5] + pc[6] + pc[7];
        int old = 0;
        if (lane == 0) old = atomicAdd(&scnt[j], tot);
        old = __shfl(old, 0);
        int pre = 0;
        #pragma unroll
        for (int c = 0; c < 8; ++c) {
          if ((m[c] >> lane) & 1ull) {
            int pos = old + pre + lane_prefix(m[c]);
            if (pos < kCap) listj[pos] = w * 1024 + (g * 8 + c) * 64 + lane;
          }
          pre += pc[c];
        }
      }
    };
    append_q(pk0, 0);
    append_q(pk1, 1);
    append_q(pk2, 2);
    append_q(pk3, 3);
  }
  __syncthreads();   // B2: all lists + counts final

  // ---- merge own list: exact fp32 re-rank (usually a single pass now) ----
  const int n = scnt[w];
  const int* bufi = reinterpret_cast<const int*>(VVb) + w * 576;
  float sv = kFltMax;
  int   si = 0x7fffffff;
  if (n <= kCap) {
    for (int g0 = 0; g0 < n; g0 += 48) {
      float mv; int mi;
      if (lane < 16) { mv = sv; mi = si; }
      else {
        int pos = g0 + (lane - 16);
        if (pos < n) {
          int jj = bufi[pos];
          float4 c = *reinterpret_cast<const float4*>(p4 + 4 * (base + jj));
          mv = d2q(qp4, c);   // bit-identical to threshold site
          mi = jj;
        } else { mv = kFltMax; mi = 0x7fffffff; }
      }
      bitonic64(mv, mi, lane);
      sv = mv; si = mi;
    }
  } else {
    // degenerate-data slow path: full direct rescan, fresh list (no dupes)
    for (int g0 = 0; g0 < kN; g0 += 48) {
      float mv; int mi;
      if (lane < 16) { mv = sv; mi = si; }
      else {
        int j = g0 + (lane - 16);
        if (j < kN) {
          float4 c = *reinterpret_cast<const float4*>(p4 + 4 * (base + j));
          mv = d2q(qp4, c);
          mi = j;
        } else { mv = kFltMax; mi = 0x7fffffff; }
      }
      bitonic64(mv, mi, lane);
      sv = mv; si = mi;
    }
  }

  int idxv = 0;
  if (lane < 16) {
    int o = si;
    if ((unsigned)o >= (unsigned)kN) o = 0;  // safety net: wrong beats fault
    idxv = o;
  }

  // fence: scan overlays (lane-mins in Ulds, lists in VVb) are dead.
  // B2 ordered all cross-wave reads of lmbuf/lists before this point.
  asm volatile("" ::: "memory");

  // ---- attention phase (wave-local LDS slices; no barrier needed) ----
  // phase 1a: gather k/v (bf16); U = bf16(q - k); VVb[row][c] = v (raw bf16)
  {
    const int r = lane >> 2, seg = lane & 3;
    const unsigned short* jrow = qkv + (base + __shfl(idxv, r)) * 192;
    const int c0 = seg * 16;
    uint4 k0 = *reinterpret_cast<const uint4*>(jrow + 64 + c0);
    uint4 k1 = *reinterpret_cast<const uint4*>(jrow + 64 + c0 + 8);
    uint4 v0 = *reinterpret_cast<const uint4*>(jrow + 128 + c0);
    uint4 v1 = *reinterpret_cast<const uint4*>(jrow + 128 + c0 + 8);
    uint4 q0 = *reinterpret_cast<const uint4*>(qkv + pt_row * 192 + c0);
    uint4 q1 = *reinterpret_cast<const uint4*>(qkv + pt_row * 192 + c0 + 8);
    auto diff2 = [](unsigned int qu, unsigned int ku) -> unsigned int {
      float lo = bflo(qu) - bflo(ku);
      float hi = bfhi(qu) - bfhi(ku);
      return pkbf(lo, hi);
    };
    uint4 u0, u1;
    u0.x = diff2(q0.x, k0.x); u0.y = diff2(q0.y, k0.y);
    u0.z = diff2(q0.z, k0.z); u0.w = diff2(q0.w, k0.w);
    u1.x = diff2(q1.x, k1.x); u1.y = diff2(q1.y, k1.y);
    u1.z = diff2(q1.z, k1.z); u1.w = diff2(q1.w, k1.w);
    *reinterpret_cast<uint4*>(&Ulds[(w * 16 + r) * 72 + c0]) = u0;
    *reinterpret_cast<uint4*>(&Ulds[(w * 16 + r) * 72 + c0 + 8]) = u1;
    *reinterpret_cast<uint4*>(&VVb[(w * 16 + r) * 72 + c0]) = v0;
    *reinterpret_cast<uint4*>(&VVb[(w * 16 + r) * 72 + c0 + 8]) = v1;
  }
  // phase 1b: pe hidden (3->32) for row l, chunk q*8 — registers only
  short8 pbf;
  {
    const int nj = __shfl(idxv, l);
    const float4 pj4 = *reinterpret_cast<const float4*>(p4 + 4 * (base + nj));
    float rx = qx - pj4.x, ry = qy - pj4.y, rz = qz - pj4.z;
    float hv[8];
    #pragma unroll
    for (int j = 0; j < 8; ++j) {
      int hh = q * 8 + j;
      hv[j] = fmaxf(pos_b1[hh] + rx * pos_w1[hh] + ry * pos_w1[32 + hh] +
                    rz * pos_w1[64 + hh], 0.0f);
    }
    union { unsigned int u[4]; short8 s; } pk;
    #pragma unroll
    for (int ii = 0; ii < 4; ++ii) pk.u[ii] = pkbf(hv[2 * ii], hv[2 * ii + 1]);
    pbf = pk.s;
  }

  // phase 2: pe = pehid @ pos_w2 (transposed MFMA, D[c][row]); RMW U and VVb
  {
    const int urow = (w * 16 + l) * 72;
    #pragma unroll
    for (int mt = 0; mt < 4; ++mt) {
      short8 paf = *reinterpret_cast<const short8*>(&pw2t[(mt * 16 + l) * 32 + q * 8]);
      f32x4 pe = __builtin_amdgcn_mfma_f32_16x16x32_bf16(paf, pbf, zero, 0, 0, 0);
      const int c0 = mt * 16 + q * 4;
      float4 b2v = *reinterpret_cast<const float4*>(&pos_b2[c0]);
      float pe0 = pe[0] + b2v.x, pe1 = pe[1] + b2v.y;
      float pe2 = pe[2] + b2v.z, pe3 = pe[3] + b2v.w;
      uint2 u2 = *reinterpret_cast<uint2*>(&Ulds[urow + c0]);
      uint2 o;
      o.x = pkbf(bflo(u2.x) + pe0, bfhi(u2.x) + pe1);
      o.y = pkbf(bflo(u2.y) + pe2, bfhi(u2.y) + pe3);
      *reinterpret_cast<uint2*>(&Ulds[urow + c0]) = o;
      uint2 v2 = *reinterpret_cast<uint2*>(&VVb[urow + c0]);
      uint2 ov;
      ov.x = pkbf(bflo(v2.x) + pe0, bfhi(v2.x) + pe1);
      ov.y = pkbf(bflo(v2.y) + pe2, bfhi(v2.y) + pe3);
      *reinterpret_cast<uint2*>(&VVb[urow + c0]) = ov;
    }
  }

  // phases 3+4 fused: per f, compute H for mt=2f,2f+1 then immediately
  // repack (2 shfl + 1 select per dword) and run GEMM2's 4 MFMAs.
  {
    f32x4 acc2[4];
    #pragma unroll
    for (int ct = 0; ct < 4; ++ct) acc2[ct] = zero;
    const int urow = (w * 16 + l) * 72;
    short8 ub0 = *reinterpret_cast<const short8*>(&Ulds[urow + q * 8]);
    short8 ub1 = *reinterpret_cast<const short8*>(&Ulds[urow + 32 + q * 8]);
    const int sbase = l + 32 * (q & 1);   // + 16*(d>>1)
    const bool hi_mt = (q >= 2);
    __builtin_amdgcn_s_setprio(1);
    #pragma unroll
    for (int f = 0; f < 8; ++f) {
      unsigned plo2[2], phi2[2];
      #pragma unroll
      for (int s = 0; s < 2; ++s) {
        const int mt = 2 * f + s;
        short8 a0 = *reinterpret_cast<const short8*>(&w1f[(mt * 2 + 0) * 512 + lane * 8]);
        short8 a1 = *reinterpret_cast<const short8*>(&w1f[(mt * 2 + 1) * 512 + lane * 8]);
        f32x4 acc = __builtin_amdgcn_mfma_f32_16x16x32_bf16(a0, ub0, zero, 0, 0, 0);
        acc = __builtin_amdgcn_mfma_f32_16x16x32_bf16(a1, ub1, acc, 0, 0, 0);
        float4 bb = *reinterpret_cast<const float4*>(&attn_b1[mt * 16 + q * 4]);
        plo2[s] = pkbf(fmaxf(acc[0] + bb.x, 0.f), fmaxf(acc[1] + bb.y, 0.f));
        phi2[s] = pkbf(fmaxf(acc[2] + bb.z, 0.f), fmaxf(acc[3] + bb.w, 0.f));
      }
      union { unsigned int u[4]; short8 s; } pk;
      #pragma unroll
      for (int d = 0; d < 4; ++d) {
        const int src = sbase + ((d >> 1) << 4);
        const unsigned int w0 = (d & 1) ? phi2[0] : plo2[0];
        const unsigned int w1v = (d & 1) ? phi2[1] : plo2[1];
        unsigned int va = (unsigned int)__shfl((int)w0, src);
        unsigned int vb = (unsigned int)__shfl((int)w1v, src);
        pk.u[d] = hi_mt ? vb : va;
      }
      short8 afr = pk.s;
      #pragma unroll
      for (int ct = 0; ct < 4; ++ct) {
        short8 bfr = *reinterpret_cast<const short8*>(&w2f[((ct * 8 + f) * 64 + lane) * 8]);
        acc2[ct] = __builtin_amdgcn_mfma_f32_16x16x32_bf16(afr, bfr, acc2[ct], 0, 0, 0);
      }
    }
    __builtin_amdgcn_s_setprio(0);
    #pragma unroll
    for (int ct = 0; ct < 4; ++ct) {
      const int ch = ct * 16 + l;
      const float bv = attn_b2[ch];
      float s0v = acc2[ct][0] + bv, s1v = acc2[ct][1] + bv;
      float s2v = acc2[ct][2] + bv, s3v = acc2[ct][3] + bv;
      float mx = fmaxf(fmaxf(s0v, s1v), fmaxf(s2v, s3v));
      mx = fmaxf(mx, __shfl_xor(mx, 16, 64));
      mx = fmaxf(mx, __shfl_xor(mx, 32, 64));
      float e0 = __expf(s0v - mx), e1 = __expf(s1v - mx);
      float e2 = __expf(s2v - mx), e3 = __expf(s3v - mx);
      float se = e0 + e1 + e2 + e3;
      se += __shfl_xor(se, 16, 64);
      se += __shfl_xor(se, 32, 64);
      const int vbase = (w * 16 + q * 4) * 72 + ch;
      float a = e0 * bfu16(VVb[vbase])       + e1 * bfu16(VVb[vbase + 72]) +
                e2 * bfu16(VVb[vbase + 144]) + e3 * bfu16(VVb[vbase + 216]);
      a += __shfl_xor(a, 16, 64);
      a += __shfl_xor(a, 32, 64);
      if (q == 0) agg[pt_row * 64 + ch] = a / se;
    }
  }
}

// ---------------- fc2 (MFMA, 64-row) + bn2+relu+residual + fused stats epilogue ----------------
__global__ __launch_bounds__(256) void fc2_mfma_kernel(
    const float* __restrict__ aggp, const float* __restrict__ hres,
    const float* __restrict__ A2, const float* __restrict__ B2,
    const unsigned short* __restrict__ fc2f, const float* __restrict__ bias,
    float* __restrict__ z, float* __restrict__ part) {
  __shared__ float SS[4][4][16], SS2[4][4][16];   // [wv][ct][l], 2 KB
  const int t = threadIdx.x, lane = t & 63, wv = t >> 6;
  const int l = lane & 15, q = lane >> 4;
  const int r0 = blockIdx.x * 64;
  const int row = r0 + wv * 16 + l;
  const f32x4 zero = {0.f, 0.f, 0.f, 0.f};
  short8 af[2];
  #pragma unroll
  for (int hh = 0; hh < 2; ++hh) {
    const int c0 = 32 * hh + q * 8;
    float4 v0 = *reinterpret_cast<const float4*>(&aggp[row * 64 + c0]);
    float4 v1 = *reinterpret_cast<const float4*>(&aggp[row * 64 + c0 + 4]);
    float4 r0v = *reinterpret_cast<const float4*>(&hres[row * 64 + c0]);
    float4 r1v = *reinterpret_cast<const float4*>(&hres[row * 64 + c0 + 4]);
    float4 Aa = *reinterpret_cast<const float4*>(&A2[c0]);
    float4 Ab = *reinterpret_cast<const float4*>(&A2[c0 + 4]);
    float4 Ba = *reinterpret_cast<const float4*>(&B2[c0]);
    float4 Bb = *reinterpret_cast<const float4*>(&B2[c0 + 4]);
    v0.x = fmaxf(Aa.x * v0.x + Ba.x, 0.f) + r0v.x;
    v0.y = fmaxf(Aa.y * v0.y + Ba.y, 0.f) + r0v.y;
    v0.z = fmaxf(Aa.z * v0.z + Ba.z, 0.f) + r0v.z;
    v0.w = fmaxf(Aa.w * v0.w + Ba.w, 0.f) + r0v.w;
    v1.x = fmaxf(Ab.x * v1.x + Bb.x, 0.f) + r1v.x;
    v1.y = fmaxf(Ab.y * v1.y + Bb.y, 0.f) + r1v.y;
    v1.z = fmaxf(Ab.z * v1.z + Bb.z, 0.f) + r1v.z;
    v1.w = fmaxf(Ab.w * v1.w + Bb.w, 0.f) + r1v.w;
    af[hh] = pack8f(v0, v1);
  }
  #pragma unroll
  for (int ct = 0; ct < 4; ++ct) {
    short8 b0 = *reinterpret_cast<const short8*>(&fc2f[((ct * 2 + 0) * 64 + lane) * 8]);
    short8 b1 = *reinterpret_cast<const short8*>(&fc2f[((ct * 2 + 1) * 64 + lane) * 8]);
    f32x4 acc = __builtin_amdgcn_mfma_f32_16x16x32_bf16(af[0], b0, zero, 0, 0, 0);
    acc = __builtin_amdgcn_mfma_f32_16x16x32_bf16(af[1], b1, acc, 0, 0, 0);
    const float bc = bias[ct * 16 + l];
    float s = 0.f, s2 = 0.f;
    #pragma unroll
    for (int i = 0; i < 4; ++i) {
      float v = acc[i] + bc;
      z[(r0 + wv * 16 + q * 4 + i) * 64 + ct * 16 + l] = v;
      s += v; s2 += v * v;
    }
    s  += __shfl_xor(s, 16, 64);  s  += __shfl_xor(s, 32, 64);
    s2 += __shfl_xor(s2, 16, 64); s2 += __shfl_xor(s2, 32, 64);
    if (q == 0) { SS[wv][ct][l] = s; SS2[wv][ct][l] = s2; }
  }
  __syncthreads();
  if (t < 64) {
    int ct = t >> 4, lc = t & 15;
    part[blockIdx.x * 128 + t] =
        SS[0][ct][lc] + SS[1][ct][lc] + SS[2][ct][lc] + SS[3][ct][lc];
    part[blockIdx.x * 128 + 64 + t] =
        SS2[0][ct][lc] + SS2[1][ct][lc] + SS2[2][ct][lc] + SS2[3][ct][lc];
  }
}

// ---------------- final bn3+relu, float4-vectorized (p-copy in pack) ----------------
__global__ void final_kernel(const float* __restrict__ z, const float* __restrict__ A3,
                             const float* __restrict__ B3, float* __restrict__ y) {
  const int i4 = (blockIdx.x * 256 + threadIdx.x) * 4;   // 1024 blocks
  const int c = i4 & 63;
  float4 zv = *reinterpret_cast<const float4*>(z + i4);
  float4 Av = *reinterpret_cast<const float4*>(A3 + c);
  float4 Bv = *reinterpret_cast<const float4*>(B3 + c);
  float4 o;
  o.x = fmaxf(Av.x * zv.x + Bv.x, 0.0f);
  o.y = fmaxf(Av.y * zv.y + Bv.y, 0.0f);
  o.z = fmaxf(Av.z * zv.z + Bv.z, 0.0f);
  o.w = fmaxf(Av.w * zv.w + Bv.w, 0.0f);
  *reinterpret_cast<float4*>(y + i4) = o;
}

extern "C" void kernel_launch(void* const* d_in, const int* in_sizes, int n_in,
                              void* d_out, int out_size, void* d_ws, size_t ws_size,
                              hipStream_t stream) {
  const float* x       = (const float*)d_in[0];
  const float* p       = (const float*)d_in[1];
  const float* fc1_w   = (const float*)d_in[2];
  const float* fc1_b   = (const float*)d_in[3];
  const float* bn1_g   = (const float*)d_in[4];
  const float* bn1_b   = (const float*)d_in[5];
  const float* qkv_w   = (const float*)d_in[6];
  const float* pos_w1  = (const float*)d_in[7];
  const float* pos_b1  = (const float*)d_in[8];
  const float* pos_w2  = (const float*)d_in[9];
  const float* pos_b2  = (const float*)d_in[10];
  const float* attn_w1 = (const float*)d_in[11];
  const float* attn_b1 = (const float*)d_in[12];
  const float* attn_w2 = (const float*)d_in[13];
  const float* attn_b2 = (const float*)d_in[14];
  const float* bn2_g   = (const float*)d_in[15];
  const float* bn2_b   = (const float*)d_in[16];
  const float* fc2_w   = (const float*)d_in[17];
  const float* fc2_b   = (const float*)d_in[18];
  const float* bn3_g   = (const float*)d_in[19];
  const float* bn3_b   = (const float*)d_in[20];

  float* ws   = (float*)d_ws;
  float* h    = ws;                     // residual, fp32
  unsigned short* qkvb = (unsigned short*)(ws + 1048576);  // bf16 [16384][192]
  float* hpre = ws + 4194304;           // fc1 out; later fc2 stats partials
  float* aggv = ws + 5242880;           // fc1 stats partials; attn agg
  float* z    = ws + 6291456;           // agg stats partials; fc2 out
  float* st   = ws + 7340032;           // A1,B1,A2,B2,A3,B3
  float* p4   = ws + 7356800;           // (x,y,z,|p|^2) packed, 16384*4
  unsigned short* wpak = (unsigned short*)(ws + 7618944);
  unsigned short* w1f  = wpak;
  unsigned short* w2f  = wpak + 16384;
  unsigned short* pw2t = wpak + 32768;
  unsigned short* wqf  = wpak + 34816;
  unsigned short* fc2f = wpak + 47104;
  unsigned short* f1wf = wpak + 51200;  // fc1_w packed, 4096 shorts

  float* A1 = st,       *B1 = st + 64;
  float* A2 = st + 128, *B2 = st + 192;
  float* A3 = st + 256, *B3 = st + 320;
  float* y = (float*)d_out;

  pack_kernel<<<216, 256, 0, stream>>>(attn_w1, attn_w2, pos_w2, qkv_w, fc2_w,
                                       fc1_w, p, p4, wpak, y);
  fc1_conv_kernel<<<256, 256, 0, stream>>>(x, f1wf, fc1_b, hpre, aggv);
  stats_fin_kernel<<<1, 1024, 0, stream>>>(aggv, bn1_g, bn1_b, A1, B1, 256);
  qkv_bn_kernel<<<256, 256, 0, stream>>>(hpre, A1, B1, wqf, h, qkvb);
  knn_attn_kernel<<<4096, 256, 0, stream>>>(p4, qkvb, pos_w1, pos_b1, pos_b2,
                                            attn_b1, attn_b2, w1f, w2f, pw2t, aggv);
  stats_part_kernel<<<256, 256, 0, stream>>>(aggv, z);
  stats_fin_kernel<<<1, 1024, 0, stream>>>(z, bn2_g, bn2_b, A2, B2, 256);
  fc2_mfma_kernel<<<256, 256, 0, stream>>>(aggv, h, A2, B2, fc2f, fc2_b, z, hpre);
  stats_fin_kernel<<<1, 1024, 0, stream>>>(hpre, bn3_g, bn3_b, A3, B3, 256);
  final_kernel<<<1024, 256, 0, stream>>>(z, A3, B3, y);
}